// Round 3
// baseline (237.126 us; speedup 1.0000x reference)
//
#include <hip/hip_runtime.h>

typedef __attribute__((ext_vector_type(8))) short s16x8;
typedef __attribute__((ext_vector_type(4))) float f32x4;

#define MFMA(a, b, c) __builtin_amdgcn_mfma_f32_16x16x32_bf16(a, b, c, 0, 0, 0)

namespace {

constexpr int Bn = 4, Nn = 2048, Hn = 12, Mn = 384;
constexpr float SCALE = 0.35355339059327379f;   // 64^-0.25
constexpr float ISM = 0.05103103630798288f;     // 1/sqrt(384)
constexpr float EPS = 1e-8f;

__device__ inline unsigned short f2b(float f) {
  unsigned u = __builtin_bit_cast(unsigned, f);
  return (unsigned short)((u + 0x7fffu + ((u >> 16) & 1u)) >> 16);
}
__device__ inline float b2f(unsigned short h) {
  unsigned u = ((unsigned)h) << 16;
  return __builtin_bit_cast(float, u);
}

__device__ inline void gl_lds16(const unsigned short* g, unsigned short* l) {
  __builtin_amdgcn_global_load_lds(
      (const __attribute__((address_space(1))) unsigned int*)g,
      (__attribute__((address_space(3))) unsigned int*)l, 16, 0, 0);
}

// ---------- conversion kernels ----------
__global__ __launch_bounds__(256) void cvt_x_k(const float* __restrict__ x,
                                               unsigned short* __restrict__ xb) {
  const int id = blockIdx.x * 256 + threadIdx.x;  // TOK*96 = 786432 threads
  const float* src = x + (size_t)id * 8;
  s16x8 o;
#pragma unroll
  for (int j = 0; j < 8; ++j) o[j] = (short)f2b(src[j]);
  *(s16x8*)(xb + (size_t)id * 8) = o;
}

// W (K=768 x Ndim) f32 -> wT (Ndim x 768) bf16
__global__ __launch_bounds__(256) void cvt_wT_k(const float* __restrict__ W,
                                                unsigned short* __restrict__ wT, int Ndim) {
  const int id = blockIdx.x * 256 + threadIdx.x;  // Ndim*96
  const int n = id / 96, kc = (id % 96) * 8;
  s16x8 o;
#pragma unroll
  for (int j = 0; j < 8; ++j) o[j] = (short)f2b(W[(size_t)(kc + j) * Ndim + n]);
  *(s16x8*)(wT + (size_t)n * 768 + kc) = o;
}

// w (H,64,384) f32 -> wt (H,384,64) bf16
__global__ __launch_bounds__(256) void cvt_wtr_k(const float* __restrict__ w,
                                                 unsigned short* __restrict__ wt) {
  const int id = blockIdx.x * 256 + threadIdx.x;  // 12*384*8 = 36864
  const int h = id / (384 * 8);
  const int r = id % (384 * 8);
  const int m = r / 8, cc = (r % 8) * 8;
  s16x8 o;
#pragma unroll
  for (int j = 0; j < 8; ++j) o[j] = (short)f2b(w[((size_t)h * 64 + cc + j) * 384 + m]);
  *(s16x8*)(wt + ((size_t)h * 384 + m) * 64 + cc) = o;
}

// ---------- 128x128 bf16 MFMA GEMM (m97 structure, global_load_lds staging) ----------
template <bool BF16OUT>
__global__ __launch_bounds__(256) void gemm_bt_k(const unsigned short* __restrict__ A,
                                                 const unsigned short* __restrict__ Bt,
                                                 int Ktot, int ldOut,
                                                 unsigned short* __restrict__ obf,
                                                 float* __restrict__ of32,
                                                 const float* __restrict__ bias) {
  __shared__ unsigned short ldsA[128 * 64];
  __shared__ unsigned short ldsB[128 * 64];
  char* lA = (char*)ldsA;
  char* lB = (char*)ldsB;
  const int t = threadIdx.x, lane = t & 63, w = t >> 6;
  const int ln = lane & 15, kg = lane >> 4;
  const size_t bm = (size_t)blockIdx.y * 128, bn = (size_t)blockIdx.x * 128;
  const int wr = w >> 1, wc = w & 1;
  const int sr = lane >> 3, s = lane & 7;
  f32x4 acc[4][4];
#pragma unroll
  for (int i = 0; i < 4; ++i)
#pragma unroll
    for (int j = 0; j < 4; ++j) acc[i][j] = (f32x4){0.f, 0.f, 0.f, 0.f};

  for (int kb = 0; kb < Ktot; kb += 64) {
    __syncthreads();  // previous compute done before overwrite
#pragma unroll
    for (int c = 0; c < 4; ++c) {
      const int row = c * 32 + w * 8 + sr;
      const int ss = (s ^ (row & 7)) * 8;  // pre-swizzled global source (rule 21)
      gl_lds16(A + (bm + row) * 768 + kb + ss, ldsA + (c * 4 + w) * 512);
      gl_lds16(Bt + (bn + row) * 768 + kb + ss, ldsB + (c * 4 + w) * 512);
    }
    __syncthreads();  // compiler drains vmcnt(0) before barrier -> data visible
#pragma unroll
    for (int ks = 0; ks < 2; ++ks) {
      s16x8 af[4], bfr[4];
#pragma unroll
      for (int mi = 0; mi < 4; ++mi) {
        const int row = wr * 64 + mi * 16 + ln;
        af[mi] = *(const s16x8*)(lA + row * 128 + (((ks * 4 + kg) ^ (row & 7)) << 4));
      }
#pragma unroll
      for (int ni = 0; ni < 4; ++ni) {
        const int row = wc * 64 + ni * 16 + ln;
        bfr[ni] = *(const s16x8*)(lB + row * 128 + (((ks * 4 + kg) ^ (row & 7)) << 4));
      }
#pragma unroll
      for (int mi = 0; mi < 4; ++mi)
#pragma unroll
        for (int ni = 0; ni < 4; ++ni) acc[mi][ni] = MFMA(af[mi], bfr[ni], acc[mi][ni]);
    }
  }
#pragma unroll
  for (int mi = 0; mi < 4; ++mi)
#pragma unroll
    for (int ni = 0; ni < 4; ++ni) {
      const size_t orow0 = bm + wr * 64 + mi * 16 + kg * 4;
      const size_t ocol = bn + wc * 64 + ni * 16 + ln;
#pragma unroll
      for (int r = 0; r < 4; ++r) {
        const float v = acc[mi][ni][r];
        if (BF16OUT)
          obf[(orow0 + r) * ldOut + ocol] = f2b(v);
        else
          of32[(orow0 + r) * ldOut + ocol] = v + bias[ocol];
      }
    }
}

// ---------- stage 2: phi(k) -> ktv partials + ksum partials ----------
// grid (8 = 4 n-groups x 2 m-halves, H, B), 512 threads
__global__ __launch_bounds__(512) void stage2_k(const unsigned short* __restrict__ qkv,
                                                const unsigned short* __restrict__ wt,
                                                float* __restrict__ ktv_part,
                                                float* __restrict__ ksum_part) {
  __shared__ unsigned short kfT[192 * 64];  // [m_local][n] swizzled, pitch 128B
  __shared__ unsigned short vt[64 * 64];    // [c][n] swizzled, pitch 128B
  __shared__ float sqh[64];
  char* kfT_b = (char*)kfT;
  char* vt_b = (char*)vt;
  const int t = threadIdx.x, lane = t & 63, w = t >> 6;
  const int ln = lane & 15, kg = lane >> 4;
  const int gx = blockIdx.x, h = blockIdx.y, b = blockIdx.z;
  const int ng = gx >> 1, mh = gx & 1, m0 = mh * 192;
  const int bh = b * Hn + h;
  const int ntile = w & 3, mgrp = w >> 2;          // GEMM1 assignment
  const int mts = (w & 3) * 3, cts = (w >> 2) * 2; // GEMM2 assignment
  f32x4 acc[3][2];
#pragma unroll
  for (int j = 0; j < 3; ++j)
#pragma unroll
    for (int i = 0; i < 2; ++i) acc[j][i] = (f32x4){0.f, 0.f, 0.f, 0.f};
  float ksr = 0.f;

  for (int ch = 0; ch < 8; ++ch) {
    const int nbase = ng * 512 + ch * 64;
    __syncthreads();
    {  // stage v (transposed) + sq-half partials
      const int n = t >> 3, c0 = (t & 7) * 8;
      const size_t tok = (size_t)b * Nn + nbase + n;
      const s16x8 vv = *(const s16x8*)(qkv + tok * 2304 + 1536 + h * 64 + c0);
#pragma unroll
      for (int j = 0; j < 8; ++j) {
        const int c = c0 + j;
        *(unsigned short*)(vt_b + c * 128 + ((2 * n) ^ ((c & 7) << 4))) = (unsigned short)vv[j];
      }
      const s16x8 kk = *(const s16x8*)(qkv + tok * 2304 + 768 + h * 64 + c0);
      float s = 0.f;
#pragma unroll
      for (int j = 0; j < 8; ++j) {
        const float f = b2f((unsigned short)kk[j]);
        s = fmaf(f, f, s);
      }
      s += __shfl_xor(s, 1);
      s += __shfl_xor(s, 2);
      s += __shfl_xor(s, 4);
      if ((t & 7) == 0) sqh[n] = 0.5f * SCALE * SCALE * s;
    }
    __syncthreads();
    {  // GEMM1: proj -> exp -> kfT (bf16, swizzled)
      const size_t tokr = (size_t)b * Nn + nbase + ntile * 16 + ln;
      const unsigned short* ap = qkv + tokr * 2304 + 768 + h * 64 + kg * 8;
      const s16x8 a0 = *(const s16x8*)ap;
      const s16x8 a1 = *(const s16x8*)(ap + 32);
      const int nr = ntile * 16 + kg * 4;
      const float s0 = sqh[nr], s1 = sqh[nr + 1], s2 = sqh[nr + 2], s3 = sqh[nr + 3];
#pragma unroll
      for (int i = 0; i < 6; ++i) {
        const int mloc = (mgrp * 6 + i) * 16 + ln;
        const unsigned short* bp = wt + ((size_t)h * 384 + m0 + mloc) * 64 + kg * 8;
        f32x4 p = (f32x4){0.f, 0.f, 0.f, 0.f};
        p = MFMA(a0, *(const s16x8*)bp, p);
        p = MFMA(a1, *(const s16x8*)(bp + 32), p);
        const float e0 = __expf(fmaf(SCALE, p[0], -s0)) * ISM;
        const float e1 = __expf(fmaf(SCALE, p[1], -s1)) * ISM;
        const float e2 = __expf(fmaf(SCALE, p[2], -s2)) * ISM;
        const float e3 = __expf(fmaf(SCALE, p[3], -s3)) * ISM;
        uint2 pk;
        pk.x = (unsigned)f2b(e0) | ((unsigned)f2b(e1) << 16);
        pk.y = (unsigned)f2b(e2) | ((unsigned)f2b(e3) << 16);
        const int bytn = 32 * ntile + 8 * kg;  // = nr*2
        *(uint2*)(kfT_b + mloc * 128 + (bytn ^ ((mloc & 7) << 4))) = pk;
      }
    }
    __syncthreads();
    if (t < 192) {  // ksum partial (waves 0-2)
#pragma unroll
      for (int s8 = 0; s8 < 8; ++s8) {
        const s16x8 v = *(const s16x8*)(kfT_b + t * 128 + ((s8 * 16) ^ ((t & 7) << 4)));
#pragma unroll
        for (int j = 0; j < 8; ++j) ksr += b2f((unsigned short)v[j]);
      }
    }
    // GEMM2: ktv += kfT @ v
#pragma unroll
    for (int half = 0; half < 2; ++half) {
      s16x8 a[3], bb[2];
#pragma unroll
      for (int j = 0; j < 3; ++j) {
        const int m = (mts + j) * 16 + ln;
        a[j] = *(const s16x8*)(kfT_b + m * 128 + ((half * 64 + kg * 16) ^ ((m & 7) << 4)));
      }
#pragma unroll
      for (int i = 0; i < 2; ++i) {
        const int c = (cts + i) * 16 + ln;
        bb[i] = *(const s16x8*)(vt_b + c * 128 + ((half * 64 + kg * 16) ^ ((c & 7) << 4)));
      }
#pragma unroll
      for (int j = 0; j < 3; ++j)
#pragma unroll
        for (int i = 0; i < 2; ++i) acc[j][i] = MFMA(a[j], bb[i], acc[j][i]);
    }
  }
  // write partials
  float* base = ktv_part + ((size_t)ng * 48 + bh) * (384 * 64);
#pragma unroll
  for (int j = 0; j < 3; ++j)
#pragma unroll
    for (int i = 0; i < 2; ++i) {
      const int mrow0 = m0 + (mts + j) * 16 + kg * 4;
      const int c = (cts + i) * 16 + ln;
#pragma unroll
      for (int r = 0; r < 4; ++r) base[(size_t)(mrow0 + r) * 64 + c] = acc[j][i][r];
    }
  if (t < 192) ksum_part[((size_t)ng * 48 + bh) * 384 + m0 + t] = ksr;
}

// ---------- reductions over the 4 n-groups -> ktv_ext [bh][80][384] bf16 ----------
// rows 0-63: ktv^T; row 64: ksum_hi; row 65: ksum_lo; rows 66-79: unused (discarded cols)
__global__ __launch_bounds__(256) void reduce_ktv_k(const float* __restrict__ part,
                                                    unsigned short* __restrict__ ktve) {
  const int bid = blockIdx.x;
  const int bh = bid / 96, chunk = bid % 96;
  const int idx = chunk * 256 + threadIdx.x;  // 0..24575
  const int m = idx >> 6, c = idx & 63;
  const size_t o = (size_t)bh * 24576 + idx;
  const size_t gs = (size_t)48 * 24576;
  const float s = part[o] + part[o + gs] + part[o + 2 * gs] + part[o + 3 * gs];
  ktve[((size_t)bh * 80 + c) * 384 + m] = f2b(s);
}
__global__ __launch_bounds__(256) void reduce_ksum_k(const float* __restrict__ partk,
                                                     unsigned short* __restrict__ ktve) {
  const int idx = blockIdx.x * 256 + threadIdx.x;  // 48*384
  const int bh = idx / 384, m = idx % 384;
  const int gs = 48 * 384;
  const float s = partk[idx] + partk[idx + gs] + partk[idx + 2 * gs] + partk[idx + 3 * gs];
  const unsigned short hi = f2b(s);
  const unsigned short lo = f2b(s - b2f(hi));
  const size_t base = ((size_t)bh * 80 + 64) * 384 + m;
  ktve[base] = hi;
  ktve[base + 384] = lo;
}

// ---------- stage 3: phi(q) -> [out | D] via one MFMA pass -> attn ----------
// grid (32, H, B), 512 threads
__global__ __launch_bounds__(512) void stage3_k(const unsigned short* __restrict__ qkv,
                                                const unsigned short* __restrict__ wt,
                                                const unsigned short* __restrict__ ktve,
                                                unsigned short* __restrict__ attn) {
  __shared__ unsigned short qf[64 * 392];  // [n][m], pitch 784B
  __shared__ float sqh[64];
  __shared__ float dpart[2][64];
  char* qf_b = (char*)qf;
  const int t = threadIdx.x, lane = t & 63, w = t >> 6;
  const int ln = lane & 15, kg = lane >> 4;
  const int nb = blockIdx.x, h = blockIdx.y, b = blockIdx.z, bh = b * Hn + h;
  const size_t tok0 = (size_t)b * Nn + nb * 64;

  {  // sq-half
    const int n = t >> 3, c0 = (t & 7) * 8;
    const s16x8 qq = *(const s16x8*)(qkv + (tok0 + n) * 2304 + h * 64 + c0);
    float s = 0.f;
#pragma unroll
    for (int j = 0; j < 8; ++j) {
      const float f = b2f((unsigned short)qq[j]);
      s = fmaf(f, f, s);
    }
    s += __shfl_xor(s, 1);
    s += __shfl_xor(s, 2);
    s += __shfl_xor(s, 4);
    if ((t & 7) == 0) sqh[n] = 0.5f * SCALE * SCALE * s;
  }
  __syncthreads();
  {  // GEMM1: proj q -> exp -> qf LDS
    const int ntile = w & 3, mg = w >> 2;
    const size_t tokr = tok0 + ntile * 16 + ln;
    const unsigned short* ap = qkv + tokr * 2304 + h * 64 + kg * 8;
    const s16x8 a0 = *(const s16x8*)ap;
    const s16x8 a1 = *(const s16x8*)(ap + 32);
    const int nr = ntile * 16 + kg * 4;
    const float s0 = sqh[nr], s1 = sqh[nr + 1], s2 = sqh[nr + 2], s3 = sqh[nr + 3];
#pragma unroll
    for (int i = 0; i < 12; ++i) {
      const int m = (mg * 12 + i) * 16 + ln;
      const unsigned short* bp = wt + ((size_t)h * 384 + m) * 64 + kg * 8;
      f32x4 p = (f32x4){0.f, 0.f, 0.f, 0.f};
      p = MFMA(a0, *(const s16x8*)bp, p);
      p = MFMA(a1, *(const s16x8*)(bp + 32), p);
      *(unsigned short*)(qf_b + (nr + 0) * 784 + m * 2) = f2b(__expf(fmaf(SCALE, p[0], -s0)) * ISM);
      *(unsigned short*)(qf_b + (nr + 1) * 784 + m * 2) = f2b(__expf(fmaf(SCALE, p[1], -s1)) * ISM);
      *(unsigned short*)(qf_b + (nr + 2) * 784 + m * 2) = f2b(__expf(fmaf(SCALE, p[2], -s2)) * ISM);
      *(unsigned short*)(qf_b + (nr + 3) * 784 + m * 2) = f2b(__expf(fmaf(SCALE, p[3], -s3)) * ISM);
    }
  }
  __syncthreads();
  // GEMM2: [out | D] = qf @ ktv_ext^T   (5 c-tiles: 4 output + 1 normalizer)
  const int ntile = w & 3, cg = w >> 2;
  const int nct = 3 - cg;          // cg0: tiles {0,1,2}; cg1: tiles {3,4}
  const int ct0 = cg ? 3 : 0;
  f32x4 acc[3];
  acc[0] = acc[1] = acc[2] = (f32x4){0.f, 0.f, 0.f, 0.f};
  const int n = ntile * 16 + ln;
  const unsigned short* bbase = ktve + (size_t)bh * 30720;
#pragma unroll
  for (int ms = 0; ms < 12; ++ms) {
    const s16x8 a = *(const s16x8*)(qf_b + n * 784 + ms * 64 + kg * 16);
#pragma unroll
    for (int i = 0; i < 3; ++i) {
      if (i < nct) {
        const int crow = (ct0 + i) * 16 + ln;
        const s16x8 bb = *(const s16x8*)(bbase + (size_t)crow * 384 + ms * 32 + kg * 8);
        acc[i] = MFMA(a, bb, acc[i]);
      }
    }
  }
  const int nr = ntile * 16 + kg * 4;
  if (cg == 1 && ln < 2) {  // D columns: 64 (hi) and 65 (lo)
#pragma unroll
    for (int r = 0; r < 4; ++r) dpart[ln][nr + r] = acc[1][r];
  }
  __syncthreads();
  // epilogue: divide by D and store bf16 attn
  float dv[4];
#pragma unroll
  for (int r = 0; r < 4; ++r) dv[r] = 1.0f / (dpart[0][nr + r] + dpart[1][nr + r] + EPS);
  const int nout = cg ? 1 : 3;
  for (int i = 0; i < nout; ++i) {
    const int c = (ct0 + i) * 16 + ln;
#pragma unroll
    for (int r = 0; r < 4; ++r)
      attn[(tok0 + nr + r) * 768 + h * 64 + c] = f2b(acc[i][r] * dv[r]);
  }
}

}  // namespace

extern "C" void kernel_launch(void* const* d_in, const int* in_sizes, int n_in,
                              void* d_out, int out_size, void* d_ws, size_t ws_size,
                              hipStream_t stream) {
  const float* x = (const float*)d_in[0];
  const float* w = (const float*)d_in[1];
  const float* Wqkv = (const float*)d_in[2];
  const float* Wproj = (const float*)d_in[3];
  const float* bproj = (const float*)d_in[4];

  char* ws = (char*)d_ws;
  // region0 (aliased): [xb 12,582,912 | wqT 3,538,944] vs [ktv_part 18,874,368 | ksum_part 294,912]
  unsigned short* xb = (unsigned short*)(ws);
  unsigned short* wqT = (unsigned short*)(ws + 12582912);
  float* ktv_part = (float*)(ws);
  float* ksum_part = (float*)(ws + 18874368);
  char* p = ws + 19169280;
  unsigned short* qkvb = (unsigned short*)p;  p += 37748736;   // (8192,2304) bf16
  unsigned short* wt = (unsigned short*)p;    p += 589824;     // (12,384,64) bf16
  unsigned short* ktve = (unsigned short*)p;  p += 2949120;    // (48,80,384) bf16
  unsigned short* attn = (unsigned short*)p;  p += 12582912;   // (8192,768) bf16
  unsigned short* wpT = (unsigned short*)p;                    // (768,768) bf16

  cvt_x_k<<<3072, 256, 0, stream>>>(x, xb);
  cvt_wT_k<<<864, 256, 0, stream>>>(Wqkv, wqT, 2304);
  cvt_wT_k<<<288, 256, 0, stream>>>(Wproj, wpT, 768);
  cvt_wtr_k<<<144, 256, 0, stream>>>(w, wt);
  gemm_bt_k<true><<<dim3(18, 64), 256, 0, stream>>>(xb, wqT, 768, 2304, qkvb, nullptr, nullptr);
  stage2_k<<<dim3(8, 12, 4), 512, 0, stream>>>(qkvb, wt, ktv_part, ksum_part);
  reduce_ktv_k<<<4608, 256, 0, stream>>>(ktv_part, ktve);
  reduce_ksum_k<<<72, 256, 0, stream>>>(ksum_part, ktve);
  stage3_k<<<dim3(32, 12, 4), 512, 0, stream>>>(qkvb, wt, ktve, attn);
  gemm_bt_k<false><<<dim3(6, 64), 256, 0, stream>>>(attn, wpT, 768, 768, nullptr,
                                                    (float*)d_out, bproj);
}

// Round 4
// 201.980 us; speedup vs baseline: 1.1740x; 1.1740x over previous
//
#include <hip/hip_runtime.h>

typedef __attribute__((ext_vector_type(8))) short s16x8;
typedef __attribute__((ext_vector_type(4))) float f32x4;

#define MFMA(a, b, c) __builtin_amdgcn_mfma_f32_16x16x32_bf16(a, b, c, 0, 0, 0)

namespace {

constexpr int Bn = 4, Nn = 2048, Hn = 12, Mn = 384;
constexpr float SCALE = 0.35355339059327379f;   // 64^-0.25
constexpr float ISM = 0.05103103630798288f;     // 1/sqrt(384)
constexpr float EPS = 1e-8f;

__device__ inline unsigned short f2b(float f) {
  unsigned u = __builtin_bit_cast(unsigned, f);
  return (unsigned short)((u + 0x7fffu + ((u >> 16) & 1u)) >> 16);
}
__device__ inline float b2f(unsigned short h) {
  unsigned u = ((unsigned)h) << 16;
  return __builtin_bit_cast(float, u);
}

__device__ inline void gl_lds16(const unsigned short* g, unsigned short* l) {
  __builtin_amdgcn_global_load_lds(
      (const __attribute__((address_space(1))) unsigned int*)g,
      (__attribute__((address_space(3))) unsigned int*)l, 16, 0, 0);
}

// ---------- conversion kernels ----------
__global__ __launch_bounds__(256) void cvt_x_k(const float* __restrict__ x,
                                               unsigned short* __restrict__ xb) {
  const int id = blockIdx.x * 256 + threadIdx.x;
  const float* src = x + (size_t)id * 8;
  s16x8 o;
#pragma unroll
  for (int j = 0; j < 8; ++j) o[j] = (short)f2b(src[j]);
  *(s16x8*)(xb + (size_t)id * 8) = o;
}

__global__ __launch_bounds__(256) void cvt_wT_k(const float* __restrict__ W,
                                                unsigned short* __restrict__ wT, int Ndim) {
  const int id = blockIdx.x * 256 + threadIdx.x;
  const int n = id / 96, kc = (id % 96) * 8;
  s16x8 o;
#pragma unroll
  for (int j = 0; j < 8; ++j) o[j] = (short)f2b(W[(size_t)(kc + j) * Ndim + n]);
  *(s16x8*)(wT + (size_t)n * 768 + kc) = o;
}

__global__ __launch_bounds__(256) void cvt_wtr_k(const float* __restrict__ w,
                                                 unsigned short* __restrict__ wt) {
  const int id = blockIdx.x * 256 + threadIdx.x;
  const int h = id / (384 * 8);
  const int r = id % (384 * 8);
  const int m = r / 8, cc = (r % 8) * 8;
  s16x8 o;
#pragma unroll
  for (int j = 0; j < 8; ++j) o[j] = (short)f2b(w[((size_t)h * 64 + cc + j) * 384 + m]);
  *(s16x8*)(wt + ((size_t)h * 384 + m) * 64 + cc) = o;
}

// ---------- 128x128 bf16 MFMA GEMM (m97 structure, global_load_lds staging) ----------
template <bool BF16OUT>
__global__ __launch_bounds__(256) void gemm_bt_k(const unsigned short* __restrict__ A,
                                                 const unsigned short* __restrict__ Bt,
                                                 int Ktot, int ldOut,
                                                 unsigned short* __restrict__ obf,
                                                 float* __restrict__ of32,
                                                 const float* __restrict__ bias) {
  __shared__ unsigned short ldsA[128 * 64];
  __shared__ unsigned short ldsB[128 * 64];
  char* lA = (char*)ldsA;
  char* lB = (char*)ldsB;
  const int t = threadIdx.x, lane = t & 63, w = t >> 6;
  const int ln = lane & 15, kg = lane >> 4;
  const size_t bm = (size_t)blockIdx.y * 128, bn = (size_t)blockIdx.x * 128;
  const int wr = w >> 1, wc = w & 1;
  const int sr = lane >> 3, s = lane & 7;
  f32x4 acc[4][4];
#pragma unroll
  for (int i = 0; i < 4; ++i)
#pragma unroll
    for (int j = 0; j < 4; ++j) acc[i][j] = (f32x4){0.f, 0.f, 0.f, 0.f};

  for (int kb = 0; kb < Ktot; kb += 64) {
    __syncthreads();
#pragma unroll
    for (int c = 0; c < 4; ++c) {
      const int row = c * 32 + w * 8 + sr;
      const int ss = (s ^ (row & 7)) * 8;
      gl_lds16(A + (bm + row) * 768 + kb + ss, ldsA + (c * 4 + w) * 512);
      gl_lds16(Bt + (bn + row) * 768 + kb + ss, ldsB + (c * 4 + w) * 512);
    }
    __syncthreads();
#pragma unroll
    for (int ks = 0; ks < 2; ++ks) {
      s16x8 af[4], bfr[4];
#pragma unroll
      for (int mi = 0; mi < 4; ++mi) {
        const int row = wr * 64 + mi * 16 + ln;
        af[mi] = *(const s16x8*)(lA + row * 128 + (((ks * 4 + kg) ^ (row & 7)) << 4));
      }
#pragma unroll
      for (int ni = 0; ni < 4; ++ni) {
        const int row = wc * 64 + ni * 16 + ln;
        bfr[ni] = *(const s16x8*)(lB + row * 128 + (((ks * 4 + kg) ^ (row & 7)) << 4));
      }
#pragma unroll
      for (int mi = 0; mi < 4; ++mi)
#pragma unroll
        for (int ni = 0; ni < 4; ++ni) acc[mi][ni] = MFMA(af[mi], bfr[ni], acc[mi][ni]);
    }
  }
#pragma unroll
  for (int mi = 0; mi < 4; ++mi)
#pragma unroll
    for (int ni = 0; ni < 4; ++ni) {
      const size_t orow0 = bm + wr * 64 + mi * 16 + kg * 4;
      const size_t ocol = bn + wc * 64 + ni * 16 + ln;
#pragma unroll
      for (int r = 0; r < 4; ++r) {
        const float v = acc[mi][ni][r];
        if (BF16OUT)
          obf[(orow0 + r) * ldOut + ocol] = f2b(v);
        else
          of32[(orow0 + r) * ldOut + ocol] = v + bias[ocol];
      }
    }
}

// ---------- stage 2 helpers ----------
template <int NCT, int CT0>
__device__ inline void s2_gemm2(const char* kfT_b, const char* vt_b, int mts, int ln, int kg,
                                f32x4 (*acc)[3]) {
#pragma unroll
  for (int half = 0; half < 2; ++half) {
    s16x8 a[3], bb[NCT];
#pragma unroll
    for (int j = 0; j < 3; ++j) {
      const int m = (mts + j) * 16 + ln;
      a[j] = *(const s16x8*)(kfT_b + m * 128 + ((half * 64 + kg * 16) ^ ((m & 7) << 4)));
    }
#pragma unroll
    for (int i = 0; i < NCT; ++i) {
      const int c = (CT0 + i) * 16 + ln;
      bb[i] = *(const s16x8*)(vt_b + c * 128 + ((half * 64 + kg * 16) ^ ((c & 7) << 4)));
    }
#pragma unroll
    for (int j = 0; j < 3; ++j)
#pragma unroll
      for (int i = 0; i < NCT; ++i) acc[j][i] = MFMA(a[j], bb[i], acc[j][i]);
  }
}

// ---------- stage 2: phi(k) -> ktv partials (+ksum via ones-column) ----------
// grid (8 = 4 n-groups x 2 m-halves, H, B), 512 threads
__global__ __launch_bounds__(512, 4) void stage2_k(const unsigned short* __restrict__ qkv,
                                                   const unsigned short* __restrict__ wt,
                                                   float* __restrict__ ktv_part,
                                                   float* __restrict__ ksum_part) {
  __shared__ unsigned short kfT[192 * 64];   // [m_local][tok] pitch 128B, swizzled
  __shared__ unsigned short vt[80 * 64];     // [c][tok] pitch 128B, swizzled; row64=1, 65-79=0
  __shared__ unsigned short wt_s[192 * 64];  // [m_local][c] pitch 128B, swizzled
  __shared__ float sqh[64];
  char* kfT_b = (char*)kfT;
  char* vt_b = (char*)vt;
  char* wt_b = (char*)wt_s;
  const int t = threadIdx.x, lane = t & 63, w = t >> 6;
  const int ln = lane & 15, kg = lane >> 4;
  const int gx = blockIdx.x, h = blockIdx.y, b = blockIdx.z;
  const int ng = gx >> 1, mh = gx & 1, m0 = mh * 192;
  const int bh = b * Hn + h;
  const int ntile = w & 3, mgrp = w >> 2;  // GEMM1 assignment
  const int mts = (w & 3) * 3;             // GEMM2: 3 m-tiles per wave
  const int cg = w >> 2;                   // GEMM2: ctiles {0,1,2} or {3,4}

  // stage wt (m0..m0+191 rows) into LDS, pre-swizzled source (rule 21)
#pragma unroll
  for (int rr = 0; rr < 3; ++rr) {
    const int j = w * 3 + rr;  // 1024-B chunk
    const int row = j * 8 + (lane >> 3), slot = lane & 7;
    gl_lds16(wt + ((size_t)h * 384 + m0 + row) * 64 + ((slot ^ (row & 7)) * 8),
             wt_s + j * 512);
  }
  // init vt rows 64..79 once: row 64 = ones (bf16 1.0), 65..79 = 0
  for (int i = t; i < 1024; i += 512) {
    const int c = 64 + (i >> 6), nn = i & 63;
    *(unsigned short*)(vt_b + c * 128 + ((2 * nn) ^ ((c & 7) << 4))) =
        (c == 64) ? (unsigned short)0x3F80 : (unsigned short)0;
  }

  f32x4 acc[3][3];
#pragma unroll
  for (int j = 0; j < 3; ++j)
#pragma unroll
    for (int i = 0; i < 3; ++i) acc[j][i] = (f32x4){0.f, 0.f, 0.f, 0.f};

  for (int ch = 0; ch < 8; ++ch) {
    const int nbase = ng * 512 + ch * 64;
    __syncthreads();  // prev GEMM2 done; (first iter: wt_s/vt-init visible after next barrier)
    {  // stage v (transposed) + k sq-half partials
      const int n = t >> 3, c0 = (t & 7) * 8;
      const size_t tok = (size_t)b * Nn + nbase + n;
      const s16x8 vv = *(const s16x8*)(qkv + tok * 2304 + 1536 + h * 64 + c0);
#pragma unroll
      for (int j = 0; j < 8; ++j) {
        const int c = c0 + j;
        *(unsigned short*)(vt_b + c * 128 + ((2 * n) ^ ((c & 7) << 4))) = (unsigned short)vv[j];
      }
      const s16x8 kk = *(const s16x8*)(qkv + tok * 2304 + 768 + h * 64 + c0);
      float s = 0.f;
#pragma unroll
      for (int j = 0; j < 8; ++j) {
        const float f = b2f((unsigned short)kk[j]);
        s = fmaf(f, f, s);
      }
      s += __shfl_xor(s, 1);
      s += __shfl_xor(s, 2);
      s += __shfl_xor(s, 4);
      if ((t & 7) == 0) sqh[n] = 0.5f * SCALE * SCALE * s;
    }
    __syncthreads();
    {  // GEMM1: proj k -> exp -> kfT (B-operand from LDS wt_s)
      const size_t tokr = (size_t)b * Nn + nbase + ntile * 16 + ln;
      const unsigned short* ap = qkv + tokr * 2304 + 768 + h * 64 + kg * 8;
      const s16x8 a0 = *(const s16x8*)ap;
      const s16x8 a1 = *(const s16x8*)(ap + 32);
      const int nr = ntile * 16 + kg * 4;
      const float s0 = sqh[nr], s1 = sqh[nr + 1], s2 = sqh[nr + 2], s3 = sqh[nr + 3];
#pragma unroll
      for (int i = 0; i < 6; ++i) {
        const int mloc = (mgrp * 6 + i) * 16 + ln;
        const s16x8 b0 = *(const s16x8*)(wt_b + mloc * 128 + ((kg ^ (mloc & 7)) << 4));
        const s16x8 b1 = *(const s16x8*)(wt_b + mloc * 128 + (((kg + 4) ^ (mloc & 7)) << 4));
        f32x4 p = (f32x4){0.f, 0.f, 0.f, 0.f};
        p = MFMA(a0, b0, p);
        p = MFMA(a1, b1, p);
        const float e0 = __expf(fmaf(SCALE, p[0], -s0)) * ISM;
        const float e1 = __expf(fmaf(SCALE, p[1], -s1)) * ISM;
        const float e2 = __expf(fmaf(SCALE, p[2], -s2)) * ISM;
        const float e3 = __expf(fmaf(SCALE, p[3], -s3)) * ISM;
        uint2 pk;
        pk.x = (unsigned)f2b(e0) | ((unsigned)f2b(e1) << 16);
        pk.y = (unsigned)f2b(e2) | ((unsigned)f2b(e3) << 16);
        const int bytn = 32 * ntile + 8 * kg;
        *(uint2*)(kfT_b + mloc * 128 + (bytn ^ ((mloc & 7) << 4))) = pk;
      }
    }
    __syncthreads();
    // GEMM2: ktv += kfT @ v  (5 c-tiles; tile 4 col 0 = ones -> ksum)
    if (cg == 0)
      s2_gemm2<3, 0>(kfT_b, vt_b, mts, ln, kg, acc);
    else
      s2_gemm2<2, 3>(kfT_b, vt_b, mts, ln, kg, acc);
  }
  // write partials
  float* base = ktv_part + ((size_t)ng * 48 + bh) * (384 * 64);
  const int nct2 = cg ? 2 : 3, ct0c = cg ? 3 : 0;
#pragma unroll
  for (int j = 0; j < 3; ++j)
#pragma unroll
    for (int i = 0; i < 3; ++i) {
      if (i >= nct2) continue;
      const int ct = ct0c + i;
      const int mrow0 = m0 + (mts + j) * 16 + kg * 4;
      if (ct < 4) {
        const int c = ct * 16 + ln;
#pragma unroll
        for (int r = 0; r < 4; ++r) base[(size_t)(mrow0 + r) * 64 + c] = acc[j][i][r];
      } else if (ln == 0) {
#pragma unroll
        for (int r = 0; r < 4; ++r)
          ksum_part[((size_t)ng * 48 + bh) * 384 + mrow0 + r] = acc[j][i][r];
      }
    }
}

// ---------- reductions over the 4 n-groups -> ktv_ext [bh][80][384] bf16 ----------
__global__ __launch_bounds__(256) void reduce_ktv_k(const float* __restrict__ part,
                                                    unsigned short* __restrict__ ktve) {
  const int bid = blockIdx.x;
  const int bh = bid / 96, chunk = bid % 96;
  const int idx = chunk * 256 + threadIdx.x;
  const int m = idx >> 6, c = idx & 63;
  const size_t o = (size_t)bh * 24576 + idx;
  const size_t gs = (size_t)48 * 24576;
  const float s = part[o] + part[o + gs] + part[o + 2 * gs] + part[o + 3 * gs];
  ktve[((size_t)bh * 80 + c) * 384 + m] = f2b(s);
}
__global__ __launch_bounds__(256) void reduce_ksum_k(const float* __restrict__ partk,
                                                     unsigned short* __restrict__ ktve) {
  const int idx = blockIdx.x * 256 + threadIdx.x;
  const int bh = idx / 384, m = idx % 384;
  const int gs = 48 * 384;
  const float s = partk[idx] + partk[idx + gs] + partk[idx + 2 * gs] + partk[idx + 3 * gs];
  const unsigned short hi = f2b(s);
  const unsigned short lo = f2b(s - b2f(hi));
  const size_t base = ((size_t)bh * 80 + 64) * 384 + m;
  ktve[base] = hi;
  ktve[base + 384] = lo;
}

// ---------- stage 3 helper ----------
template <int NCT, int CT0>
__device__ inline void s3_gemm2(const char* qf_b, const unsigned short* bbase, int n, int ln,
                                int kg, f32x4* acc2) {
#pragma unroll
  for (int msC = 0; msC < 12; msC += 4) {
    s16x8 bb[4][NCT];
#pragma unroll
    for (int mm = 0; mm < 4; ++mm)
#pragma unroll
      for (int i = 0; i < NCT; ++i) {
        const int crow = (CT0 + i) * 16 + ln;
        bb[mm][i] = *(const s16x8*)(bbase + (size_t)crow * 384 + (msC + mm) * 32 + kg * 8);
      }
#pragma unroll
    for (int mm = 0; mm < 4; ++mm) {
      const int col = (msC + mm) * 64 + kg * 16;
      const s16x8 a = *(const s16x8*)(qf_b + n * 768 + (col ^ ((n & 15) << 4)));
#pragma unroll
      for (int i = 0; i < NCT; ++i) acc2[i] = MFMA(a, bb[mm][i], acc2[i]);
    }
  }
}

// ---------- stage 3: phi(q) (sq_q & ISM cancel) -> [out|D] -> attn ----------
// grid (32, H, B), 512 threads
__global__ __launch_bounds__(512, 3) void stage3_k(const unsigned short* __restrict__ qkv,
                                                   const unsigned short* __restrict__ wt,
                                                   const unsigned short* __restrict__ ktve,
                                                   unsigned short* __restrict__ attn) {
  __shared__ unsigned short qf[64 * 384];  // [n][m] pitch 768B, XOR-swizzled (n&15)<<4
  __shared__ float dpart[2][64];
  char* qf_b = (char*)qf;
  const int t = threadIdx.x, lane = t & 63, w = t >> 6;
  const int ln = lane & 15, kg = lane >> 4;
  const int nb = blockIdx.x, h = blockIdx.y, b = blockIdx.z, bh = b * Hn + h;
  const size_t tok0 = (size_t)b * Nn + nb * 64;

  {  // GEMM1: 3 m-tiles x 4 n-tiles per wave; 14 independent upfront loads
    s16x8 a0[4], a1[4], b0[3], b1[3];
#pragma unroll
    for (int nt = 0; nt < 4; ++nt) {
      const unsigned short* ap = qkv + (tok0 + nt * 16 + ln) * 2304 + h * 64 + kg * 8;
      a0[nt] = *(const s16x8*)ap;
      a1[nt] = *(const s16x8*)(ap + 32);
    }
#pragma unroll
    for (int i = 0; i < 3; ++i) {
      const int m = (w * 3 + i) * 16 + ln;
      const unsigned short* bp = wt + ((size_t)h * 384 + m) * 64 + kg * 8;
      b0[i] = *(const s16x8*)bp;
      b1[i] = *(const s16x8*)(bp + 32);
    }
    f32x4 acc[3][4];
#pragma unroll
    for (int i = 0; i < 3; ++i)
#pragma unroll
      for (int nt = 0; nt < 4; ++nt) {
        f32x4 p = (f32x4){0.f, 0.f, 0.f, 0.f};
        p = MFMA(a0[nt], b0[i], p);
        p = MFMA(a1[nt], b1[i], p);
        acc[i][nt] = p;
      }
#pragma unroll
    for (int i = 0; i < 3; ++i) {
      const int m = (w * 3 + i) * 16 + ln;
#pragma unroll
      for (int nt = 0; nt < 4; ++nt) {
#pragma unroll
        for (int r = 0; r < 4; ++r) {
          const int n = nt * 16 + kg * 4 + r;
          const float e = __expf(SCALE * acc[i][nt][r]);  // sq_q & ISM cancel in num/D
          *(unsigned short*)(qf_b + n * 768 + ((2 * m) ^ ((n & 15) << 4))) = f2b(e);
        }
      }
    }
  }
  __syncthreads();
  // GEMM2: [out|D] = qf @ ktve^T (5 c-tiles: 4 output + 1 normalizer)
  const int ntile = w & 3, cg = w >> 2;
  const int ct0 = cg ? 3 : 0;
  f32x4 acc2[3];
  acc2[0] = acc2[1] = acc2[2] = (f32x4){0.f, 0.f, 0.f, 0.f};
  const int n = ntile * 16 + ln;
  const unsigned short* bbase = ktve + (size_t)bh * 30720;
  if (cg == 0)
    s3_gemm2<3, 0>(qf_b, bbase, n, ln, kg, acc2);
  else
    s3_gemm2<2, 3>(qf_b, bbase, n, ln, kg, acc2);
  const int nr = ntile * 16 + kg * 4;
  if (cg == 1 && ln < 2) {
#pragma unroll
    for (int r = 0; r < 4; ++r) dpart[ln][nr + r] = acc2[1][r];
  }
  __syncthreads();
  float dv[4];
#pragma unroll
  for (int r = 0; r < 4; ++r) dv[r] = 1.0f / (dpart[0][nr + r] + dpart[1][nr + r] + EPS);
  const int nout = cg ? 1 : 3;
  for (int i = 0; i < nout; ++i) {
    const int c = (ct0 + i) * 16 + ln;
#pragma unroll
    for (int r = 0; r < 4; ++r)
      attn[(tok0 + nr + r) * 768 + h * 64 + c] = f2b(acc2[i][r] * dv[r]);
  }
}

}  // namespace

extern "C" void kernel_launch(void* const* d_in, const int* in_sizes, int n_in,
                              void* d_out, int out_size, void* d_ws, size_t ws_size,
                              hipStream_t stream) {
  const float* x = (const float*)d_in[0];
  const float* w = (const float*)d_in[1];
  const float* Wqkv = (const float*)d_in[2];
  const float* Wproj = (const float*)d_in[3];
  const float* bproj = (const float*)d_in[4];

  char* ws = (char*)d_ws;
  unsigned short* xb = (unsigned short*)(ws);
  unsigned short* wqT = (unsigned short*)(ws + 12582912);
  float* ktv_part = (float*)(ws);
  float* ksum_part = (float*)(ws + 18874368);
  char* p = ws + 19169280;
  unsigned short* qkvb = (unsigned short*)p;  p += 37748736;   // (8192,2304) bf16
  unsigned short* wt = (unsigned short*)p;    p += 589824;     // (12,384,64) bf16
  unsigned short* ktve = (unsigned short*)p;  p += 2949120;    // (48,80,384) bf16
  unsigned short* attn = (unsigned short*)p;  p += 12582912;   // (8192,768) bf16
  unsigned short* wpT = (unsigned short*)p;                    // (768,768) bf16

  cvt_x_k<<<3072, 256, 0, stream>>>(x, xb);
  cvt_wT_k<<<864, 256, 0, stream>>>(Wqkv, wqT, 2304);
  cvt_wT_k<<<288, 256, 0, stream>>>(Wproj, wpT, 768);
  cvt_wtr_k<<<144, 256, 0, stream>>>(w, wt);
  gemm_bt_k<true><<<dim3(18, 64), 256, 0, stream>>>(xb, wqT, 768, 2304, qkvb, nullptr, nullptr);
  stage2_k<<<dim3(8, 12, 4), 512, 0, stream>>>(qkvb, wt, ktv_part, ksum_part);
  reduce_ktv_k<<<4608, 256, 0, stream>>>(ktv_part, ktve);
  reduce_ksum_k<<<72, 256, 0, stream>>>(ksum_part, ktve);
  stage3_k<<<dim3(32, 12, 4), 512, 0, stream>>>(qkvb, wt, ktve, attn);
  gemm_bt_k<false><<<dim3(6, 64), 256, 0, stream>>>(attn, wpT, 768, 768, nullptr,
                                                    (float*)d_out, bproj);
}

// Round 5
// 162.336 us; speedup vs baseline: 1.4607x; 1.2442x over previous
//
#include <hip/hip_runtime.h>

typedef __attribute__((ext_vector_type(8))) short s16x8;
typedef __attribute__((ext_vector_type(4))) float f32x4;

#define MFMA(a, b, c) __builtin_amdgcn_mfma_f32_16x16x32_bf16(a, b, c, 0, 0, 0)

namespace {

constexpr int Bn = 4, Nn = 2048, Hn = 12, Mn = 384;
constexpr float SCALE = 0.35355339059327379f;   // 64^-0.25
constexpr float ISM = 0.05103103630798288f;     // 1/sqrt(384)
constexpr float EPS = 1e-8f;

__device__ inline unsigned short f2b(float f) {
  unsigned u = __builtin_bit_cast(unsigned, f);
  return (unsigned short)((u + 0x7fffu + ((u >> 16) & 1u)) >> 16);
}
__device__ inline float b2f(unsigned short h) {
  unsigned u = ((unsigned)h) << 16;
  return __builtin_bit_cast(float, u);
}

__device__ inline void gl_lds16(const unsigned short* g, unsigned short* l) {
  __builtin_amdgcn_global_load_lds(
      (const __attribute__((address_space(1))) unsigned int*)g,
      (__attribute__((address_space(3))) unsigned int*)l, 16, 0, 0);
}

// ---------- conversion kernels ----------
__global__ __launch_bounds__(256) void cvt_x_k(const float* __restrict__ x,
                                               unsigned short* __restrict__ xb) {
  const int id = blockIdx.x * 256 + threadIdx.x;
  const float* src = x + (size_t)id * 8;
  s16x8 o;
#pragma unroll
  for (int j = 0; j < 8; ++j) o[j] = (short)f2b(src[j]);
  *(s16x8*)(xb + (size_t)id * 8) = o;
}

__global__ __launch_bounds__(256) void cvt_wT_k(const float* __restrict__ W,
                                                unsigned short* __restrict__ wT, int Ndim) {
  const int id = blockIdx.x * 256 + threadIdx.x;
  const int n = id / 96, kc = (id % 96) * 8;
  s16x8 o;
#pragma unroll
  for (int j = 0; j < 8; ++j) o[j] = (short)f2b(W[(size_t)(kc + j) * Ndim + n]);
  *(s16x8*)(wT + (size_t)n * 768 + kc) = o;
}

__global__ __launch_bounds__(256) void cvt_wtr_k(const float* __restrict__ w,
                                                 unsigned short* __restrict__ wt) {
  const int id = blockIdx.x * 256 + threadIdx.x;
  const int h = id / (384 * 8);
  const int r = id % (384 * 8);
  const int m = r / 8, cc = (r % 8) * 8;
  s16x8 o;
#pragma unroll
  for (int j = 0; j < 8; ++j) o[j] = (short)f2b(w[((size_t)h * 64 + cc + j) * 384 + m]);
  *(s16x8*)(wt + ((size_t)h * 384 + m) * 64 + cc) = o;
}

// ---------- 128x128 bf16 MFMA GEMM (m97 structure, global_load_lds staging) ----------
template <bool BF16OUT>
__global__ __launch_bounds__(256) void gemm_bt_k(const unsigned short* __restrict__ A,
                                                 const unsigned short* __restrict__ Bt,
                                                 int Ktot, int ldOut,
                                                 unsigned short* __restrict__ obf,
                                                 float* __restrict__ of32,
                                                 const float* __restrict__ bias) {
  __shared__ unsigned short ldsA[128 * 64];
  __shared__ unsigned short ldsB[128 * 64];
  char* lA = (char*)ldsA;
  char* lB = (char*)ldsB;
  const int t = threadIdx.x, lane = t & 63, w = t >> 6;
  const int ln = lane & 15, kg = lane >> 4;
  const size_t bm = (size_t)blockIdx.y * 128, bn = (size_t)blockIdx.x * 128;
  const int wr = w >> 1, wc = w & 1;
  const int sr = lane >> 3, s = lane & 7;
  f32x4 acc[4][4];
#pragma unroll
  for (int i = 0; i < 4; ++i)
#pragma unroll
    for (int j = 0; j < 4; ++j) acc[i][j] = (f32x4){0.f, 0.f, 0.f, 0.f};

  for (int kb = 0; kb < Ktot; kb += 64) {
    __syncthreads();
#pragma unroll
    for (int c = 0; c < 4; ++c) {
      const int row = c * 32 + w * 8 + sr;
      const int ss = (s ^ (row & 7)) * 8;
      gl_lds16(A + (bm + row) * 768 + kb + ss, ldsA + (c * 4 + w) * 512);
      gl_lds16(Bt + (bn + row) * 768 + kb + ss, ldsB + (c * 4 + w) * 512);
    }
    __syncthreads();
#pragma unroll
    for (int ks = 0; ks < 2; ++ks) {
      s16x8 af[4], bfr[4];
#pragma unroll
      for (int mi = 0; mi < 4; ++mi) {
        const int row = wr * 64 + mi * 16 + ln;
        af[mi] = *(const s16x8*)(lA + row * 128 + (((ks * 4 + kg) ^ (row & 7)) << 4));
      }
#pragma unroll
      for (int ni = 0; ni < 4; ++ni) {
        const int row = wc * 64 + ni * 16 + ln;
        bfr[ni] = *(const s16x8*)(lB + row * 128 + (((ks * 4 + kg) ^ (row & 7)) << 4));
      }
#pragma unroll
      for (int mi = 0; mi < 4; ++mi)
#pragma unroll
        for (int ni = 0; ni < 4; ++ni) acc[mi][ni] = MFMA(af[mi], bfr[ni], acc[mi][ni]);
    }
  }
#pragma unroll
  for (int mi = 0; mi < 4; ++mi)
#pragma unroll
    for (int ni = 0; ni < 4; ++ni) {
      const size_t orow0 = bm + wr * 64 + mi * 16 + kg * 4;
      const size_t ocol = bn + wc * 64 + ni * 16 + ln;
#pragma unroll
      for (int r = 0; r < 4; ++r) {
        const float v = acc[mi][ni][r];
        if (BF16OUT)
          obf[(orow0 + r) * ldOut + ocol] = f2b(v);
        else
          of32[(orow0 + r) * ldOut + ocol] = v + bias[ocol];
      }
    }
}

// ---------- stage 2 helpers ----------
template <int NCT, int CT0>
__device__ inline void s2_gemm2(const char* kfT_b, const char* vt_b, int mts, int ln, int kg,
                                f32x4 (*acc)[3]) {
#pragma unroll
  for (int half = 0; half < 2; ++half) {
    s16x8 a[3], bb[NCT];
#pragma unroll
    for (int j = 0; j < 3; ++j) {
      const int m = (mts + j) * 16 + ln;
      a[j] = *(const s16x8*)(kfT_b + m * 128 + ((half * 64 + kg * 16) ^ ((m & 7) << 4)));
    }
#pragma unroll
    for (int i = 0; i < NCT; ++i) {
      const int c = (CT0 + i) * 16 + ln;
      bb[i] = *(const s16x8*)(vt_b + c * 128 + ((half * 64 + kg * 16) ^ ((c & 7) << 4)));
    }
#pragma unroll
    for (int j = 0; j < 3; ++j)
#pragma unroll
      for (int i = 0; i < NCT; ++i) acc[j][i] = MFMA(a[j], bb[i], acc[j][i]);
  }
}

// ---------- stage 2: phi(k) -> ktv partials (+ksum via ones-column) ----------
// grid (8 = 4 n-groups x 2 m-halves, H, B), 512 threads
__global__ __launch_bounds__(512, 4) void stage2_k(const unsigned short* __restrict__ qkv,
                                                   const unsigned short* __restrict__ wt,
                                                   float* __restrict__ ktv_part,
                                                   float* __restrict__ ksum_part) {
  __shared__ unsigned short kfT[192 * 64];   // [m_local][tok] pitch 128B, swizzled
  __shared__ unsigned short vt[80 * 64];     // [c][tok] pitch 128B, swizzled; row64=1, 65-79=0
  __shared__ unsigned short wt_s[192 * 64];  // [m_local][c] pitch 128B, swizzled
  __shared__ unsigned short k_s[64 * 64];    // [tok][c] pitch 128B, swizzled
  __shared__ float sqh[64];
  char* kfT_b = (char*)kfT;
  char* vt_b = (char*)vt;
  char* wt_b = (char*)wt_s;
  char* k_b = (char*)k_s;
  const int t = threadIdx.x, lane = t & 63, w = t >> 6;
  const int ln = lane & 15, kg = lane >> 4;
  const int gx = blockIdx.x, h = blockIdx.y, b = blockIdx.z;
  const int ng = gx >> 1, mh = gx & 1, m0 = mh * 192;
  const int bh = b * Hn + h;
  const int ntile = w & 3, mgrp = w >> 2;  // GEMM1 assignment
  const int mts = (w & 3) * 3;             // GEMM2: 3 m-tiles per wave
  const int cg = w >> 2;                   // GEMM2: ctiles {0,1,2} or {3,4}

  // stage wt (m0..m0+191 rows) into LDS, pre-swizzled source (rule 21)
#pragma unroll
  for (int rr = 0; rr < 3; ++rr) {
    const int j = w * 3 + rr;  // 1024-B chunk
    const int row = j * 8 + (lane >> 3), slot = lane & 7;
    gl_lds16(wt + ((size_t)h * 384 + m0 + row) * 64 + ((slot ^ (row & 7)) * 8),
             wt_s + j * 512);
  }
  // init vt rows 64..79 once: row 64 = ones (bf16 1.0), 65..79 = 0
  for (int i = t; i < 1024; i += 512) {
    const int c = 64 + (i >> 6), nn = i & 63;
    *(unsigned short*)(vt_b + c * 128 + ((2 * nn) ^ ((c & 7) << 4))) =
        (c == 64) ? (unsigned short)0x3F80 : (unsigned short)0;
  }

  f32x4 acc[3][3];
#pragma unroll
  for (int j = 0; j < 3; ++j)
#pragma unroll
    for (int i = 0; i < 3; ++i) acc[j][i] = (f32x4){0.f, 0.f, 0.f, 0.f};

  for (int ch = 0; ch < 8; ++ch) {
    const int nbase = ng * 512 + ch * 64;
    __syncthreads();  // prev GEMM2 done; kfT/vt/k_s free
    {  // stage k tile coalesced via global_load_lds (pre-swizzled source)
      const int row = w * 8 + (lane >> 3), slot = lane & 7;
      gl_lds16(qkv + ((size_t)b * Nn + nbase + row) * 2304 + 768 + h * 64 +
                   ((slot ^ (row & 7)) * 8),
               k_s + w * 512);
    }
    {  // stage v (transposed scatter)
      const int n = t >> 3, c0 = (t & 7) * 8;
      const size_t tok = (size_t)b * Nn + nbase + n;
      const s16x8 vv = *(const s16x8*)(qkv + tok * 2304 + 1536 + h * 64 + c0);
#pragma unroll
      for (int j = 0; j < 8; ++j) {
        const int c = c0 + j;
        *(unsigned short*)(vt_b + c * 128 + ((2 * n) ^ ((c & 7) << 4))) = (unsigned short)vv[j];
      }
    }
    __syncthreads();  // k_s (vmcnt drained at barrier) + vt ready
    {  // sq-half from k_s
      const int n = t >> 3, sl = t & 7;
      const s16x8 kk = *(const s16x8*)(k_b + n * 128 + ((sl ^ (n & 7)) << 4));
      float s = 0.f;
#pragma unroll
      for (int j = 0; j < 8; ++j) {
        const float f = b2f((unsigned short)kk[j]);
        s = fmaf(f, f, s);
      }
      s += __shfl_xor(s, 1);
      s += __shfl_xor(s, 2);
      s += __shfl_xor(s, 4);
      if ((t & 7) == 0) sqh[n] = 0.5f * SCALE * SCALE * s;
    }
    __syncthreads();  // sqh ready
    {  // GEMM1: proj k -> exp -> kfT (A from k_s, B from wt_s)
      const int arow = ntile * 16 + ln;
      const s16x8 a0 = *(const s16x8*)(k_b + arow * 128 + ((kg ^ (arow & 7)) << 4));
      const s16x8 a1 = *(const s16x8*)(k_b + arow * 128 + (((kg + 4) ^ (arow & 7)) << 4));
      const int nr = ntile * 16 + kg * 4;
      const float s0 = sqh[nr], s1 = sqh[nr + 1], s2 = sqh[nr + 2], s3 = sqh[nr + 3];
#pragma unroll
      for (int i = 0; i < 6; ++i) {
        const int mloc = (mgrp * 6 + i) * 16 + ln;
        const s16x8 b0 = *(const s16x8*)(wt_b + mloc * 128 + ((kg ^ (mloc & 7)) << 4));
        const s16x8 b1 = *(const s16x8*)(wt_b + mloc * 128 + (((kg + 4) ^ (mloc & 7)) << 4));
        f32x4 p = (f32x4){0.f, 0.f, 0.f, 0.f};
        p = MFMA(a0, b0, p);
        p = MFMA(a1, b1, p);
        const float e0 = __expf(fmaf(SCALE, p[0], -s0)) * ISM;
        const float e1 = __expf(fmaf(SCALE, p[1], -s1)) * ISM;
        const float e2 = __expf(fmaf(SCALE, p[2], -s2)) * ISM;
        const float e3 = __expf(fmaf(SCALE, p[3], -s3)) * ISM;
        uint2 pk;
        pk.x = (unsigned)f2b(e0) | ((unsigned)f2b(e1) << 16);
        pk.y = (unsigned)f2b(e2) | ((unsigned)f2b(e3) << 16);
        const int bytn = 32 * ntile + 8 * kg;
        *(uint2*)(kfT_b + mloc * 128 + (bytn ^ ((mloc & 7) << 4))) = pk;
      }
    }
    __syncthreads();
    // GEMM2: ktv += kfT @ v  (5 c-tiles; tile 4 col 0 = ones -> ksum)
    if (cg == 0)
      s2_gemm2<3, 0>(kfT_b, vt_b, mts, ln, kg, acc);
    else
      s2_gemm2<2, 3>(kfT_b, vt_b, mts, ln, kg, acc);
  }
  // write partials
  float* base = ktv_part + ((size_t)ng * 48 + bh) * (384 * 64);
  const int nct2 = cg ? 2 : 3, ct0c = cg ? 3 : 0;
#pragma unroll
  for (int j = 0; j < 3; ++j)
#pragma unroll
    for (int i = 0; i < 3; ++i) {
      if (i >= nct2) continue;
      const int ct = ct0c + i;
      const int mrow0 = m0 + (mts + j) * 16 + kg * 4;
      if (ct < 4) {
        const int c = ct * 16 + ln;
#pragma unroll
        for (int r = 0; r < 4; ++r) base[(size_t)(mrow0 + r) * 64 + c] = acc[j][i][r];
      } else if (ln == 0) {
#pragma unroll
        for (int r = 0; r < 4; ++r)
          ksum_part[((size_t)ng * 48 + bh) * 384 + mrow0 + r] = acc[j][i][r];
      }
    }
}

// ---------- reductions over the 4 n-groups -> ktv_ext [bh][80][384] bf16 ----------
__global__ __launch_bounds__(256) void reduce_ktv_k(const float* __restrict__ part,
                                                    unsigned short* __restrict__ ktve) {
  const int bid = blockIdx.x;
  const int bh = bid / 96, chunk = bid % 96;
  const int idx = chunk * 256 + threadIdx.x;
  const int m = idx >> 6, c = idx & 63;
  const size_t o = (size_t)bh * 24576 + idx;
  const size_t gs = (size_t)48 * 24576;
  const float s = part[o] + part[o + gs] + part[o + 2 * gs] + part[o + 3 * gs];
  ktve[((size_t)bh * 80 + c) * 384 + m] = f2b(s);
}
__global__ __launch_bounds__(256) void reduce_ksum_k(const float* __restrict__ partk,
                                                     unsigned short* __restrict__ ktve) {
  const int idx = blockIdx.x * 256 + threadIdx.x;
  const int bh = idx / 384, m = idx % 384;
  const int gs = 48 * 384;
  const float s = partk[idx] + partk[idx + gs] + partk[idx + 2 * gs] + partk[idx + 3 * gs];
  const unsigned short hi = f2b(s);
  const unsigned short lo = f2b(s - b2f(hi));
  const size_t base = ((size_t)bh * 80 + 64) * 384 + m;
  ktve[base] = hi;
  ktve[base + 384] = lo;
}

// ---------- stage 3: fused phi(q)+attn, all staging coalesced ----------
// grid (16, H, B), 512 threads; 128 tokens/block; 6 m-chunks of 64, dbuf wt/ktve
__global__ __launch_bounds__(512, 4) void stage3_k(const unsigned short* __restrict__ qkv,
                                                   const unsigned short* __restrict__ wt,
                                                   const unsigned short* __restrict__ ktve,
                                                   unsigned short* __restrict__ attn) {
  __shared__ unsigned short q_s[128 * 64];      // [tok][c] swizzled, 16KB
  __shared__ unsigned short qf_s[128 * 64];     // [tok][m_chunk] swizzled, wave-private rows
  __shared__ unsigned short wt_s[2][64 * 64];   // [m][c] swizzled, 8KB each
  __shared__ unsigned short kt_s[2][80 * 64];   // [cext][m_chunk] swizzled, 10KB each
  char* q_b = (char*)q_s;
  char* qf_b = (char*)qf_s;
  const int t = threadIdx.x, lane = t & 63, w = t >> 6;
  const int ln = lane & 15, kg = lane >> 4;
  const int nb = blockIdx.x, h = blockIdx.y, b = blockIdx.z, bh = b * Hn + h;
  const size_t tok0 = (size_t)b * Nn + nb * 128;
  const int lr = lane >> 3, sl = lane & 7;

  // stage q tile (128 rows x 128B), 2 gl_lds16 per wave
#pragma unroll
  for (int rr = 0; rr < 2; ++rr) {
    const int row = w * 16 + rr * 8 + lr;
    gl_lds16(qkv + (tok0 + row) * 2304 + h * 64 + ((sl ^ (row & 7)) * 8),
             q_s + (w * 16 + rr * 8) * 64 + lane * 8);
  }
  // chunk stagers
  auto stage_wt = [&](int mc, int pb) {
    const int row = w * 8 + lr;
    gl_lds16(wt + ((size_t)h * 384 + mc * 64 + row) * 64 + ((sl ^ (row & 7)) * 8),
             wt_s[pb] + w * 512 + lane * 8);
  };
  auto stage_kt = [&](int mc, int pb) {
    const int row = w * 8 + lr;
    gl_lds16(ktve + ((size_t)bh * 80 + row) * 384 + mc * 64 + ((sl ^ (row & 7)) * 8),
             kt_s[pb] + w * 512 + lane * 8);
    if (w < 2) {
      const int row2 = 64 + w * 8 + lr;
      gl_lds16(ktve + ((size_t)bh * 80 + row2) * 384 + mc * 64 + ((sl ^ (row2 & 7)) * 8),
               kt_s[pb] + (64 + w * 8) * 64 + lane * 8);
    }
  };
  stage_wt(0, 0);
  stage_kt(0, 0);
  __syncthreads();  // q + chunk0 ready (barrier drains vmcnt)

  f32x4 acc2[5];
#pragma unroll
  for (int i = 0; i < 5; ++i) acc2[i] = (f32x4){0.f, 0.f, 0.f, 0.f};

  const int arow = w * 16 + ln;          // this wave's A-row (token) for both GEMMs
  const char* qrow = q_b + arow * 128;
  const int asw = (arow & 7) << 4;

  for (int mc = 0; mc < 6; ++mc) {
    const int pb = mc & 1;
    if (mc < 5) {
      stage_wt(mc + 1, pb ^ 1);
      stage_kt(mc + 1, pb ^ 1);
    }
    // GEMM1: proj[tok 16][m 64] for this wave's token tile
    const s16x8 af0 = *(const s16x8*)(qrow + ((kg << 4) ^ asw));
    const s16x8 af1 = *(const s16x8*)(qrow + (((kg + 4) << 4) ^ asw));
    const char* wb = (const char*)wt_s[pb];
    f32x4 p[4];
#pragma unroll
    for (int mt = 0; mt < 4; ++mt) {
      const int mrow = mt * 16 + ln;
      const s16x8 b0 = *(const s16x8*)(wb + mrow * 128 + ((kg ^ (mrow & 7)) << 4));
      const s16x8 b1 = *(const s16x8*)(wb + mrow * 128 + (((kg + 4) ^ (mrow & 7)) << 4));
      f32x4 pp = (f32x4){0.f, 0.f, 0.f, 0.f};
      pp = MFMA(af0, b0, pp);
      p[mt] = MFMA(af1, b1, pp);
    }
    // exp -> qf (wave-private rows; sq_q and ISM cancel in num/D)
#pragma unroll
    for (int mt = 0; mt < 4; ++mt) {
#pragma unroll
      for (int r = 0; r < 4; ++r) {
        const int trow = w * 16 + kg * 4 + r;
        const int m = mt * 16 + ln;
        *(unsigned short*)(qf_b + trow * 128 + ((2 * m) ^ ((trow & 7) << 4))) =
            f2b(__expf(SCALE * p[mt][r]));
      }
    }
    // GEMM2: acc2 += qf(tile) @ kt^T  (same-wave LDS dep only; no barrier)
    const char* qfr = qf_b + arow * 128;
    const s16x8 a0 = *(const s16x8*)(qfr + ((kg << 4) ^ asw));
    const s16x8 a1 = *(const s16x8*)(qfr + (((kg + 4) << 4) ^ asw));
    const char* kb = (const char*)kt_s[pb];
#pragma unroll
    for (int ct = 0; ct < 5; ++ct) {
      const int crow = ct * 16 + ln;
      const s16x8 b0 = *(const s16x8*)(kb + crow * 128 + ((kg ^ (crow & 7)) << 4));
      const s16x8 b1 = *(const s16x8*)(kb + crow * 128 + (((kg + 4) ^ (crow & 7)) << 4));
      acc2[ct] = MFMA(a0, b0, acc2[ct]);
      acc2[ct] = MFMA(a1, b1, acc2[ct]);
    }
    __syncthreads();  // all waves done with buf pb; next stage may overwrite
  }
  // D from c-tile 4 (cols 64=hi, 65=lo) via shuffles; tokens match acc rows
  float dv[4];
#pragma unroll
  for (int r = 0; r < 4; ++r) {
    const float hi = __shfl(acc2[4][r], (lane & 48));
    const float lo = __shfl(acc2[4][r], (lane & 48) | 1);
    dv[r] = 1.0f / (hi + lo + EPS);
  }
#pragma unroll
  for (int ct = 0; ct < 4; ++ct) {
#pragma unroll
    for (int r = 0; r < 4; ++r) {
      const int trow = w * 16 + kg * 4 + r;
      const int c = ct * 16 + ln;
      attn[(tok0 + trow) * 768 + h * 64 + c] = f2b(acc2[ct][r] * dv[r]);
    }
  }
}

}  // namespace

extern "C" void kernel_launch(void* const* d_in, const int* in_sizes, int n_in,
                              void* d_out, int out_size, void* d_ws, size_t ws_size,
                              hipStream_t stream) {
  const float* x = (const float*)d_in[0];
  const float* w = (const float*)d_in[1];
  const float* Wqkv = (const float*)d_in[2];
  const float* Wproj = (const float*)d_in[3];
  const float* bproj = (const float*)d_in[4];

  char* ws = (char*)d_ws;
  unsigned short* xb = (unsigned short*)(ws);
  unsigned short* wqT = (unsigned short*)(ws + 12582912);
  float* ktv_part = (float*)(ws);
  float* ksum_part = (float*)(ws + 18874368);
  char* p = ws + 19169280;
  unsigned short* qkvb = (unsigned short*)p;  p += 37748736;   // (8192,2304) bf16
  unsigned short* wt = (unsigned short*)p;    p += 589824;     // (12,384,64) bf16
  unsigned short* ktve = (unsigned short*)p;  p += 2949120;    // (48,80,384) bf16
  unsigned short* attn = (unsigned short*)p;  p += 12582912;   // (8192,768) bf16
  unsigned short* wpT = (unsigned short*)p;                    // (768,768) bf16

  cvt_x_k<<<3072, 256, 0, stream>>>(x, xb);
  cvt_wT_k<<<864, 256, 0, stream>>>(Wqkv, wqT, 2304);
  cvt_wT_k<<<288, 256, 0, stream>>>(Wproj, wpT, 768);
  cvt_wtr_k<<<144, 256, 0, stream>>>(w, wt);
  gemm_bt_k<true><<<dim3(18, 64), 256, 0, stream>>>(xb, wqT, 768, 2304, qkvb, nullptr, nullptr);
  stage2_k<<<dim3(8, 12, 4), 512, 0, stream>>>(qkvb, wt, ktv_part, ksum_part);
  reduce_ktv_k<<<4608, 256, 0, stream>>>(ktv_part, ktve);
  reduce_ksum_k<<<72, 256, 0, stream>>>(ksum_part, ktve);
  stage3_k<<<dim3(16, 12, 4), 512, 0, stream>>>(qkvb, wt, ktve, attn);
  gemm_bt_k<false><<<dim3(6, 64), 256, 0, stream>>>(attn, wpT, 768, 768, nullptr,
                                                    (float*)d_out, bproj);
}

// Round 6
// 158.047 us; speedup vs baseline: 1.5004x; 1.0271x over previous
//
#include <hip/hip_runtime.h>

typedef __attribute__((ext_vector_type(8))) short s16x8;
typedef __attribute__((ext_vector_type(4))) float f32x4;

#define MFMA(a, b, c) __builtin_amdgcn_mfma_f32_16x16x32_bf16(a, b, c, 0, 0, 0)

namespace {

constexpr int Bn = 4, Nn = 2048, Hn = 12, Mn = 384;
constexpr float SCALE = 0.35355339059327379f;   // 64^-0.25
constexpr float ISM = 0.05103103630798288f;     // 1/sqrt(384)
constexpr float EPS = 1e-8f;

__device__ inline unsigned short f2b(float f) {
  unsigned u = __builtin_bit_cast(unsigned, f);
  return (unsigned short)((u + 0x7fffu + ((u >> 16) & 1u)) >> 16);
}
__device__ inline float b2f(unsigned short h) {
  unsigned u = ((unsigned)h) << 16;
  return __builtin_bit_cast(float, u);
}

__device__ inline void gl_lds16(const unsigned short* g, unsigned short* l) {
  __builtin_amdgcn_global_load_lds(
      (const __attribute__((address_space(1))) unsigned int*)g,
      (__attribute__((address_space(3))) unsigned int*)l, 16, 0, 0);
}

// ---------- merged conversion kernel ----------
// grid: [0,3072) cvt_x | [3072,3936) wqT | [3936,4224) wpT | [4224,4368) wtr
__global__ __launch_bounds__(256) void cvt_all_k(const float* __restrict__ x,
                                                 const float* __restrict__ Wqkv,
                                                 const float* __restrict__ Wproj,
                                                 const float* __restrict__ w,
                                                 unsigned short* __restrict__ xb,
                                                 unsigned short* __restrict__ wqT,
                                                 unsigned short* __restrict__ wpT,
                                                 unsigned short* __restrict__ wt) {
  const int bid = blockIdx.x;
  if (bid < 3072) {
    const int id = bid * 256 + threadIdx.x;
    const float* src = x + (size_t)id * 8;
    s16x8 o;
#pragma unroll
    for (int j = 0; j < 8; ++j) o[j] = (short)f2b(src[j]);
    *(s16x8*)(xb + (size_t)id * 8) = o;
  } else if (bid < 3936) {
    const int id = (bid - 3072) * 256 + threadIdx.x;
    const int n = id / 96, kc = (id % 96) * 8;
    s16x8 o;
#pragma unroll
    for (int j = 0; j < 8; ++j) o[j] = (short)f2b(Wqkv[(size_t)(kc + j) * 2304 + n]);
    *(s16x8*)(wqT + (size_t)n * 768 + kc) = o;
  } else if (bid < 4224) {
    const int id = (bid - 3936) * 256 + threadIdx.x;
    const int n = id / 96, kc = (id % 96) * 8;
    s16x8 o;
#pragma unroll
    for (int j = 0; j < 8; ++j) o[j] = (short)f2b(Wproj[(size_t)(kc + j) * 768 + n]);
    *(s16x8*)(wpT + (size_t)n * 768 + kc) = o;
  } else {
    const int id = (bid - 4224) * 256 + threadIdx.x;  // 36864 total
    const int h = id / (384 * 8);
    const int r = id % (384 * 8);
    const int m = r / 8, cc = (r % 8) * 8;
    s16x8 o;
#pragma unroll
    for (int j = 0; j < 8; ++j) o[j] = (short)f2b(w[((size_t)h * 64 + cc + j) * 384 + m]);
    *(s16x8*)(wt + ((size_t)h * 384 + m) * 64 + cc) = o;
  }
}

// ---------- 128x128 bf16 MFMA GEMM: stage-early double-buffered (T3 minimal) ----------
template <bool BF16OUT>
__global__ __launch_bounds__(256) void gemm_bt_k(const unsigned short* __restrict__ A,
                                                 const unsigned short* __restrict__ Bt,
                                                 int Ktot, int ldOut,
                                                 unsigned short* __restrict__ obf,
                                                 float* __restrict__ of32,
                                                 const float* __restrict__ bias) {
  __shared__ unsigned short ldsA[2][128 * 64];
  __shared__ unsigned short ldsB[2][128 * 64];
  const int t = threadIdx.x, lane = t & 63, w = t >> 6;
  const int ln = lane & 15, kg = lane >> 4;
  const size_t bm = (size_t)blockIdx.y * 128, bn = (size_t)blockIdx.x * 128;
  const int wr = w >> 1, wc = w & 1;
  const int sr = lane >> 3, s = lane & 7;
  f32x4 acc[4][4];
#pragma unroll
  for (int i = 0; i < 4; ++i)
#pragma unroll
    for (int j = 0; j < 4; ++j) acc[i][j] = (f32x4){0.f, 0.f, 0.f, 0.f};

  auto stage = [&](int kb, int d) {
#pragma unroll
    for (int c = 0; c < 4; ++c) {
      const int row = c * 32 + w * 8 + sr;
      const int ss = (s ^ (row & 7)) * 8;  // pre-swizzled global source (rule 21)
      gl_lds16(A + (bm + row) * 768 + kb + ss, &ldsA[d][(c * 4 + w) * 512]);
      gl_lds16(Bt + (bn + row) * 768 + kb + ss, &ldsB[d][(c * 4 + w) * 512]);
    }
  };

  const int nt = Ktot / 64;
  stage(0, 0);
  for (int ti = 0; ti < nt; ++ti) {
    const int cur = ti & 1;
    __syncthreads();  // drains vmcnt: tile ti landed; all waves done with buf cur^1
    if (ti + 1 < nt) stage((ti + 1) * 64, cur ^ 1);  // issue-early; hides under compute
    const char* lA = (const char*)ldsA[cur];
    const char* lB = (const char*)ldsB[cur];
#pragma unroll
    for (int ks = 0; ks < 2; ++ks) {
      s16x8 af[4], bfr[4];
#pragma unroll
      for (int mi = 0; mi < 4; ++mi) {
        const int row = wr * 64 + mi * 16 + ln;
        af[mi] = *(const s16x8*)(lA + row * 128 + (((ks * 4 + kg) ^ (row & 7)) << 4));
      }
#pragma unroll
      for (int ni = 0; ni < 4; ++ni) {
        const int row = wc * 64 + ni * 16 + ln;
        bfr[ni] = *(const s16x8*)(lB + row * 128 + (((ks * 4 + kg) ^ (row & 7)) << 4));
      }
#pragma unroll
      for (int mi = 0; mi < 4; ++mi)
#pragma unroll
        for (int ni = 0; ni < 4; ++ni) acc[mi][ni] = MFMA(af[mi], bfr[ni], acc[mi][ni]);
    }
  }
#pragma unroll
  for (int mi = 0; mi < 4; ++mi)
#pragma unroll
    for (int ni = 0; ni < 4; ++ni) {
      const size_t orow0 = bm + wr * 64 + mi * 16 + kg * 4;
      const size_t ocol = bn + wc * 64 + ni * 16 + ln;
#pragma unroll
      for (int r = 0; r < 4; ++r) {
        const float v = acc[mi][ni][r];
        if (BF16OUT)
          obf[(orow0 + r) * ldOut + ocol] = f2b(v);
        else
          of32[(orow0 + r) * ldOut + ocol] = v + bias[ocol];
      }
    }
}

// ---------- stage 2 helpers ----------
template <int NCT, int CT0>
__device__ inline void s2_gemm2(const char* kfT_b, const char* vt_b, int mts, int ln, int kg,
                                f32x4 (*acc)[3]) {
#pragma unroll
  for (int half = 0; half < 2; ++half) {
    s16x8 a[3], bb[NCT];
#pragma unroll
    for (int j = 0; j < 3; ++j) {
      const int m = (mts + j) * 16 + ln;
      a[j] = *(const s16x8*)(kfT_b + m * 128 + ((half * 64 + kg * 16) ^ ((m & 7) << 4)));
    }
#pragma unroll
    for (int i = 0; i < NCT; ++i) {
      const int c = (CT0 + i) * 16 + ln;
      bb[i] = *(const s16x8*)(vt_b + c * 128 + ((half * 64 + kg * 16) ^ ((c & 7) << 4)));
    }
#pragma unroll
    for (int j = 0; j < 3; ++j)
#pragma unroll
      for (int i = 0; i < NCT; ++i) acc[j][i] = MFMA(a[j], bb[i], acc[j][i]);
  }
}

// ---------- stage 2: phi(k) -> ktv partials (+ksum via ones-column) ----------
// grid (8 = 4 n-groups x 2 m-halves, H, B), 512 threads; stage-early chunk pipeline
__global__ __launch_bounds__(512, 4) void stage2_k(const unsigned short* __restrict__ qkv,
                                                   const unsigned short* __restrict__ wt,
                                                   float* __restrict__ ktv_part,
                                                   float* __restrict__ ksum_part) {
  __shared__ unsigned short kfT[192 * 64];   // [m_local][tok] pitch 128B, swizzled
  __shared__ unsigned short vt[80 * 64];     // [c][tok] pitch 128B, swizzled; row64=1, 65-79=0
  __shared__ unsigned short wt_s[192 * 64];  // [m_local][c] pitch 128B, swizzled
  __shared__ unsigned short k_s[64 * 64];    // [tok][c] pitch 128B, swizzled
  __shared__ float sqh[64];
  char* kfT_b = (char*)kfT;
  char* vt_b = (char*)vt;
  char* wt_b = (char*)wt_s;
  char* k_b = (char*)k_s;
  const int t = threadIdx.x, lane = t & 63, w = t >> 6;
  const int ln = lane & 15, kg = lane >> 4;
  const int gx = blockIdx.x, h = blockIdx.y, b = blockIdx.z;
  const int ng = gx >> 1, mh = gx & 1, m0 = mh * 192;
  const int bh = b * Hn + h;
  const int ntile = w & 3, mgrp = w >> 2;  // GEMM1 assignment
  const int mts = (w & 3) * 3;             // GEMM2: 3 m-tiles per wave
  const int cg = w >> 2;                   // GEMM2: ctiles {0,1,2} or {3,4}
  const int lr = lane >> 3, sl = lane & 7;

  auto stage_k = [&](int ch) {
    const int row = w * 8 + lr;
    gl_lds16(qkv + ((size_t)b * Nn + ng * 512 + ch * 64 + row) * 2304 + 768 + h * 64 +
                 ((sl ^ (row & 7)) * 8),
             k_s + w * 512);
  };
  const int vn = t >> 3, vc0 = (t & 7) * 8;
  auto load_v = [&](int ch) {
    return *(const s16x8*)(qkv + ((size_t)b * Nn + ng * 512 + ch * 64 + vn) * 2304 + 1536 +
                           h * 64 + vc0);
  };
  auto scat_v = [&](s16x8 vv) {
#pragma unroll
    for (int j = 0; j < 8; ++j) {
      const int c = vc0 + j;
      *(unsigned short*)(vt_b + c * 128 + ((2 * vn) ^ ((c & 7) << 4))) = (unsigned short)vv[j];
    }
  };
  auto do_sq = [&]() {
    const int n = t >> 3, slq = t & 7;
    const s16x8 kk = *(const s16x8*)(k_b + n * 128 + ((slq ^ (n & 7)) << 4));
    float sacc = 0.f;
#pragma unroll
    for (int j = 0; j < 8; ++j) {
      const float f = b2f((unsigned short)kk[j]);
      sacc = fmaf(f, f, sacc);
    }
    sacc += __shfl_xor(sacc, 1);
    sacc += __shfl_xor(sacc, 2);
    sacc += __shfl_xor(sacc, 4);
    if ((t & 7) == 0) sqh[n] = 0.5f * SCALE * SCALE * sacc;
  };

  // ---- prologue: wt tile + vt tail init + chunk 0 k/v
#pragma unroll
  for (int rr = 0; rr < 3; ++rr) {
    const int j = w * 3 + rr;  // 1024-B chunk
    const int row = j * 8 + lr;
    gl_lds16(wt + ((size_t)h * 384 + m0 + row) * 64 + ((sl ^ (row & 7)) * 8), wt_s + j * 512);
  }
  for (int i = t; i < 1024; i += 512) {
    const int c = 64 + (i >> 6), nn = i & 63;
    *(unsigned short*)(vt_b + c * 128 + ((2 * nn) ^ ((c & 7) << 4))) =
        (c == 64) ? (unsigned short)0x3F80 : (unsigned short)0;
  }
  stage_k(0);
  s16x8 vreg = load_v(0);
  __syncthreads();  // wt_s, k_s(0), vt-init landed
  scat_v(vreg);
  do_sq();
  __syncthreads();  // vt(0), sqh(0) ready

  f32x4 acc[3][3];
#pragma unroll
  for (int j = 0; j < 3; ++j)
#pragma unroll
    for (int i = 0; i < 3; ++i) acc[j][i] = (f32x4){0.f, 0.f, 0.f, 0.f};

  for (int ch = 0; ch < 8; ++ch) {
    {  // GEMM1: proj k -> exp -> kfT (A from k_s, B from wt_s)
      const int arow = ntile * 16 + ln;
      const s16x8 a0 = *(const s16x8*)(k_b + arow * 128 + ((kg ^ (arow & 7)) << 4));
      const s16x8 a1 = *(const s16x8*)(k_b + arow * 128 + (((kg + 4) ^ (arow & 7)) << 4));
      const int nr = ntile * 16 + kg * 4;
      const float s0 = sqh[nr], s1 = sqh[nr + 1], s2 = sqh[nr + 2], s3 = sqh[nr + 3];
#pragma unroll
      for (int i = 0; i < 6; ++i) {
        const int mloc = (mgrp * 6 + i) * 16 + ln;
        const s16x8 b0 = *(const s16x8*)(wt_b + mloc * 128 + ((kg ^ (mloc & 7)) << 4));
        const s16x8 b1 = *(const s16x8*)(wt_b + mloc * 128 + (((kg + 4) ^ (mloc & 7)) << 4));
        f32x4 p = (f32x4){0.f, 0.f, 0.f, 0.f};
        p = MFMA(a0, b0, p);
        p = MFMA(a1, b1, p);
        const float e0 = __expf(fmaf(SCALE, p[0], -s0)) * ISM;
        const float e1 = __expf(fmaf(SCALE, p[1], -s1)) * ISM;
        const float e2 = __expf(fmaf(SCALE, p[2], -s2)) * ISM;
        const float e3 = __expf(fmaf(SCALE, p[3], -s3)) * ISM;
        uint2 pk;
        pk.x = (unsigned)f2b(e0) | ((unsigned)f2b(e1) << 16);
        pk.y = (unsigned)f2b(e2) | ((unsigned)f2b(e3) << 16);
        const int bytn = 32 * ntile + 8 * kg;
        *(uint2*)(kfT_b + mloc * 128 + (bytn ^ ((mloc & 7) << 4))) = pk;
      }
    }
    __syncthreads();  // kfT visible; all waves done reading k_s(ch)
    if (ch < 7) {     // issue next chunk's k DMA + v reg-load; hide under GEMM2
      stage_k(ch + 1);
      vreg = load_v(ch + 1);
    }
    if (cg == 0)
      s2_gemm2<3, 0>(kfT_b, vt_b, mts, ln, kg, acc);
    else
      s2_gemm2<2, 3>(kfT_b, vt_b, mts, ln, kg, acc);
    __syncthreads();  // GEMM2 done (vt free); vmcnt drained -> k_s(ch+1) landed
    if (ch < 7) {
      scat_v(vreg);
      do_sq();
      __syncthreads();  // vt(ch+1), sqh(ch+1) ready
    }
  }
  // write partials
  float* base = ktv_part + ((size_t)ng * 48 + bh) * (384 * 64);
  const int nct2 = cg ? 2 : 3, ct0c = cg ? 3 : 0;
#pragma unroll
  for (int j = 0; j < 3; ++j)
#pragma unroll
    for (int i = 0; i < 3; ++i) {
      if (i >= nct2) continue;
      const int ct = ct0c + i;
      const int mrow0 = m0 + (mts + j) * 16 + kg * 4;
      if (ct < 4) {
        const int c = ct * 16 + ln;
#pragma unroll
        for (int r = 0; r < 4; ++r) base[(size_t)(mrow0 + r) * 64 + c] = acc[j][i][r];
      } else if (ln == 0) {
#pragma unroll
        for (int r = 0; r < 4; ++r)
          ksum_part[((size_t)ng * 48 + bh) * 384 + mrow0 + r] = acc[j][i][r];
      }
    }
}

// ---------- merged reduction over the 4 n-groups -> ktv_ext [bh][80][384] bf16 ----------
// grid: [0,4608) ktv | [4608,4680) ksum hi/lo
__global__ __launch_bounds__(256) void reduce_all_k(const float* __restrict__ part,
                                                    const float* __restrict__ partk,
                                                    unsigned short* __restrict__ ktve) {
  const int bid = blockIdx.x;
  if (bid < 4608) {
    const int bh = bid / 96, chunk = bid % 96;
    const int idx = chunk * 256 + threadIdx.x;
    const int m = idx >> 6, c = idx & 63;
    const size_t o = (size_t)bh * 24576 + idx;
    const size_t gs = (size_t)48 * 24576;
    const float s = part[o] + part[o + gs] + part[o + 2 * gs] + part[o + 3 * gs];
    ktve[((size_t)bh * 80 + c) * 384 + m] = f2b(s);
  } else {
    const int idx = (bid - 4608) * 256 + threadIdx.x;
    const int bh = idx / 384, m = idx % 384;
    const int gs = 48 * 384;
    const float s = partk[idx] + partk[idx + gs] + partk[idx + 2 * gs] + partk[idx + 3 * gs];
    const unsigned short hi = f2b(s);
    const unsigned short lo = f2b(s - b2f(hi));
    const size_t base = ((size_t)bh * 80 + 64) * 384 + m;
    ktve[base] = hi;
    ktve[base + 384] = lo;
  }
}

// ---------- stage 3: fused phi(q)+attn, all staging coalesced ----------
// grid (16, H, B), 512 threads; 128 tokens/block; 6 m-chunks of 64, dbuf wt/ktve
__global__ __launch_bounds__(512, 4) void stage3_k(const unsigned short* __restrict__ qkv,
                                                   const unsigned short* __restrict__ wt,
                                                   const unsigned short* __restrict__ ktve,
                                                   unsigned short* __restrict__ attn) {
  __shared__ unsigned short q_s[128 * 64];      // [tok][c] swizzled, 16KB
  __shared__ unsigned short qf_s[128 * 64];     // [tok][m_chunk] swizzled, wave-private rows
  __shared__ unsigned short wt_s[2][64 * 64];   // [m][c] swizzled, 8KB each
  __shared__ unsigned short kt_s[2][80 * 64];   // [cext][m_chunk] swizzled, 10KB each
  char* q_b = (char*)q_s;
  char* qf_b = (char*)qf_s;
  const int t = threadIdx.x, lane = t & 63, w = t >> 6;
  const int ln = lane & 15, kg = lane >> 4;
  const int nb = blockIdx.x, h = blockIdx.y, b = blockIdx.z, bh = b * Hn + h;
  const size_t tok0 = (size_t)b * Nn + nb * 128;
  const int lr = lane >> 3, sl = lane & 7;

  // stage q tile (128 rows x 128B), 2 gl_lds16 per wave
#pragma unroll
  for (int rr = 0; rr < 2; ++rr) {
    const int row = w * 16 + rr * 8 + lr;
    gl_lds16(qkv + (tok0 + row) * 2304 + h * 64 + ((sl ^ (row & 7)) * 8),
             q_s + (w * 16 + rr * 8) * 64 + lane * 8);
  }
  // chunk stagers
  auto stage_wt = [&](int mc, int pb) {
    const int row = w * 8 + lr;
    gl_lds16(wt + ((size_t)h * 384 + mc * 64 + row) * 64 + ((sl ^ (row & 7)) * 8),
             wt_s[pb] + w * 512 + lane * 8);
  };
  auto stage_kt = [&](int mc, int pb) {
    const int row = w * 8 + lr;
    gl_lds16(ktve + ((size_t)bh * 80 + row) * 384 + mc * 64 + ((sl ^ (row & 7)) * 8),
             kt_s[pb] + w * 512 + lane * 8);
    if (w < 2) {
      const int row2 = 64 + w * 8 + lr;
      gl_lds16(ktve + ((size_t)bh * 80 + row2) * 384 + mc * 64 + ((sl ^ (row2 & 7)) * 8),
               kt_s[pb] + (64 + w * 8) * 64 + lane * 8);
    }
  };
  stage_wt(0, 0);
  stage_kt(0, 0);
  __syncthreads();  // q + chunk0 ready (barrier drains vmcnt)

  f32x4 acc2[5];
#pragma unroll
  for (int i = 0; i < 5; ++i) acc2[i] = (f32x4){0.f, 0.f, 0.f, 0.f};

  const int arow = w * 16 + ln;          // this wave's A-row (token) for both GEMMs
  const char* qrow = q_b + arow * 128;
  const int asw = (arow & 7) << 4;

  for (int mc = 0; mc < 6; ++mc) {
    const int pb = mc & 1;
    if (mc < 5) {
      stage_wt(mc + 1, pb ^ 1);
      stage_kt(mc + 1, pb ^ 1);
    }
    // GEMM1: proj[tok 16][m 64] for this wave's token tile
    const s16x8 af0 = *(const s16x8*)(qrow + ((kg << 4) ^ asw));
    const s16x8 af1 = *(const s16x8*)(qrow + (((kg + 4) << 4) ^ asw));
    const char* wb = (const char*)wt_s[pb];
    f32x4 p[4];
#pragma unroll
    for (int mt = 0; mt < 4; ++mt) {
      const int mrow = mt * 16 + ln;
      const s16x8 b0 = *(const s16x8*)(wb + mrow * 128 + ((kg ^ (mrow & 7)) << 4));
      const s16x8 b1 = *(const s16x8*)(wb + mrow * 128 + (((kg + 4) ^ (mrow & 7)) << 4));
      f32x4 pp = (f32x4){0.f, 0.f, 0.f, 0.f};
      pp = MFMA(af0, b0, pp);
      p[mt] = MFMA(af1, b1, pp);
    }
    // exp -> qf (wave-private rows; sq_q and ISM cancel in num/D)
#pragma unroll
    for (int mt = 0; mt < 4; ++mt) {
#pragma unroll
      for (int r = 0; r < 4; ++r) {
        const int trow = w * 16 + kg * 4 + r;
        const int m = mt * 16 + ln;
        *(unsigned short*)(qf_b + trow * 128 + ((2 * m) ^ ((trow & 7) << 4))) =
            f2b(__expf(SCALE * p[mt][r]));
      }
    }
    // GEMM2: acc2 += qf(tile) @ kt^T  (same-wave LDS dep only; no barrier)
    const char* qfr = qf_b + arow * 128;
    const s16x8 a0 = *(const s16x8*)(qfr + ((kg << 4) ^ asw));
    const s16x8 a1 = *(const s16x8*)(qfr + (((kg + 4) << 4) ^ asw));
    const char* kb = (const char*)kt_s[pb];
#pragma unroll
    for (int ct = 0; ct < 5; ++ct) {
      const int crow = ct * 16 + ln;
      const s16x8 b0 = *(const s16x8*)(kb + crow * 128 + ((kg ^ (crow & 7)) << 4));
      const s16x8 b1 = *(const s16x8*)(kb + crow * 128 + (((kg + 4) ^ (crow & 7)) << 4));
      acc2[ct] = MFMA(a0, b0, acc2[ct]);
      acc2[ct] = MFMA(a1, b1, acc2[ct]);
    }
    __syncthreads();  // all waves done with buf pb; next stage may overwrite
  }
  // D from c-tile 4 (cols 64=hi, 65=lo) via shuffles; tokens match acc rows
  float dv[4];
#pragma unroll
  for (int r = 0; r < 4; ++r) {
    const float hi = __shfl(acc2[4][r], (lane & 48));
    const float lo = __shfl(acc2[4][r], (lane & 48) | 1);
    dv[r] = 1.0f / (hi + lo + EPS);
  }
#pragma unroll
  for (int ct = 0; ct < 4; ++ct) {
#pragma unroll
    for (int r = 0; r < 4; ++r) {
      const int trow = w * 16 + kg * 4 + r;
      const int c = ct * 16 + ln;
      attn[(tok0 + trow) * 768 + h * 64 + c] = f2b(acc2[ct][r] * dv[r]);
    }
  }
}

}  // namespace

extern "C" void kernel_launch(void* const* d_in, const int* in_sizes, int n_in,
                              void* d_out, int out_size, void* d_ws, size_t ws_size,
                              hipStream_t stream) {
  const float* x = (const float*)d_in[0];
  const float* w = (const float*)d_in[1];
  const float* Wqkv = (const float*)d_in[2];
  const float* Wproj = (const float*)d_in[3];
  const float* bproj = (const float*)d_in[4];

  char* ws = (char*)d_ws;
  unsigned short* xb = (unsigned short*)(ws);
  unsigned short* wqT = (unsigned short*)(ws + 12582912);
  float* ktv_part = (float*)(ws);
  float* ksum_part = (float*)(ws + 18874368);
  char* p = ws + 19169280;
  unsigned short* qkvb = (unsigned short*)p;  p += 37748736;   // (8192,2304) bf16
  unsigned short* wt = (unsigned short*)p;    p += 589824;     // (12,384,64) bf16
  unsigned short* ktve = (unsigned short*)p;  p += 2949120;    // (48,80,384) bf16
  unsigned short* attn = (unsigned short*)p;  p += 12582912;   // (8192,768) bf16
  unsigned short* wpT = (unsigned short*)p;                    // (768,768) bf16

  cvt_all_k<<<4368, 256, 0, stream>>>(x, Wqkv, Wproj, w, xb, wqT, wpT, wt);
  gemm_bt_k<true><<<dim3(18, 64), 256, 0, stream>>>(xb, wqT, 768, 2304, qkvb, nullptr, nullptr);
  stage2_k<<<dim3(8, 12, 4), 512, 0, stream>>>(qkvb, wt, ktv_part, ksum_part);
  reduce_all_k<<<4680, 256, 0, stream>>>(ktv_part, ksum_part, ktve);
  stage3_k<<<dim3(16, 12, 4), 512, 0, stream>>>(qkvb, wt, ktve, attn);
  gemm_bt_k<false><<<dim3(6, 64), 256, 0, stream>>>(attn, wpT, 768, 768, nullptr,
                                                    (float*)d_out, bproj);
}

// Round 7
// 149.615 us; speedup vs baseline: 1.5849x; 1.0564x over previous
//
#include <hip/hip_runtime.h>

typedef __attribute__((ext_vector_type(8))) short s16x8;
typedef __attribute__((ext_vector_type(4))) float f32x4;

#define MFMA(a, b, c) __builtin_amdgcn_mfma_f32_16x16x32_bf16(a, b, c, 0, 0, 0)

namespace {

constexpr int Bn = 4, Nn = 2048, Hn = 12, Mn = 384;
constexpr float SCALE = 0.35355339059327379f;   // 64^-0.25
constexpr float ISM = 0.05103103630798288f;     // 1/sqrt(384)
constexpr float EPS = 1e-8f;

__device__ inline unsigned short f2b(float f) {
  unsigned u = __builtin_bit_cast(unsigned, f);
  return (unsigned short)((u + 0x7fffu + ((u >> 16) & 1u)) >> 16);
}
__device__ inline float b2f(unsigned short h) {
  unsigned u = ((unsigned)h) << 16;
  return __builtin_bit_cast(float, u);
}

__device__ inline void gl_lds16(const unsigned short* g, unsigned short* l) {
  __builtin_amdgcn_global_load_lds(
      (const __attribute__((address_space(1))) unsigned int*)g,
      (__attribute__((address_space(3))) unsigned int*)l, 16, 0, 0);
}

// ---------- merged conversion kernel ----------
// grid: [0,3072) cvt_x | [3072,3936) wqT | [3936,4224) wpT | [4224,4368) wtr
__global__ __launch_bounds__(256) void cvt_all_k(const float* __restrict__ x,
                                                 const float* __restrict__ Wqkv,
                                                 const float* __restrict__ Wproj,
                                                 const float* __restrict__ w,
                                                 unsigned short* __restrict__ xb,
                                                 unsigned short* __restrict__ wqT,
                                                 unsigned short* __restrict__ wpT,
                                                 unsigned short* __restrict__ wt) {
  const int bid = blockIdx.x;
  if (bid < 3072) {
    const int id = bid * 256 + threadIdx.x;
    const float* src = x + (size_t)id * 8;
    s16x8 o;
#pragma unroll
    for (int j = 0; j < 8; ++j) o[j] = (short)f2b(src[j]);
    *(s16x8*)(xb + (size_t)id * 8) = o;
  } else if (bid < 3936) {
    const int id = (bid - 3072) * 256 + threadIdx.x;
    const int n = id / 96, kc = (id % 96) * 8;
    s16x8 o;
#pragma unroll
    for (int j = 0; j < 8; ++j) o[j] = (short)f2b(Wqkv[(size_t)(kc + j) * 2304 + n]);
    *(s16x8*)(wqT + (size_t)n * 768 + kc) = o;
  } else if (bid < 4224) {
    const int id = (bid - 3936) * 256 + threadIdx.x;
    const int n = id / 96, kc = (id % 96) * 8;
    s16x8 o;
#pragma unroll
    for (int j = 0; j < 8; ++j) o[j] = (short)f2b(Wproj[(size_t)(kc + j) * 768 + n]);
    *(s16x8*)(wpT + (size_t)n * 768 + kc) = o;
  } else {
    const int id = (bid - 4224) * 256 + threadIdx.x;  // 36864 total
    const int h = id / (384 * 8);
    const int r = id % (384 * 8);
    const int m = r / 8, cc = (r % 8) * 8;
    s16x8 o;
#pragma unroll
    for (int j = 0; j < 8; ++j) o[j] = (short)f2b(w[((size_t)h * 64 + cc + j) * 384 + m]);
    *(s16x8*)(wt + ((size_t)h * 384 + m) * 64 + cc) = o;
  }
}

// ---------- qkv GEMM: 128x128, single-buffer 2-barrier (m97) + XCD swizzle ----------
__global__ __launch_bounds__(256) void gemm_qkv_k(const unsigned short* __restrict__ A,
                                                  const unsigned short* __restrict__ Bt,
                                                  unsigned short* __restrict__ obf) {
  __shared__ unsigned short ldsA[128 * 64];
  __shared__ unsigned short ldsB[128 * 64];
  char* lA = (char*)ldsA;
  char* lB = (char*)ldsB;
  const int t = threadIdx.x, lane = t & 63, w = t >> 6;
  const int ln = lane & 15, kg = lane >> 4;
  // XCD-aware bijective swizzle: nwg=1152, 1152%8==0
  const int flat = blockIdx.y * 18 + blockIdx.x;
  const int swz = (flat & 7) * 144 + (flat >> 3);
  const size_t bm = (size_t)(swz / 18) * 128, bn = (size_t)(swz % 18) * 128;
  const int wr = w >> 1, wc = w & 1;
  const int sr = lane >> 3, s = lane & 7;
  f32x4 acc[4][4];
#pragma unroll
  for (int i = 0; i < 4; ++i)
#pragma unroll
    for (int j = 0; j < 4; ++j) acc[i][j] = (f32x4){0.f, 0.f, 0.f, 0.f};

  for (int kb = 0; kb < 768; kb += 64) {
    __syncthreads();  // previous compute done before overwrite
#pragma unroll
    for (int c = 0; c < 4; ++c) {
      const int row = c * 32 + w * 8 + sr;
      const int ss = (s ^ (row & 7)) * 8;  // pre-swizzled global source (rule 21)
      gl_lds16(A + (bm + row) * 768 + kb + ss, ldsA + (c * 4 + w) * 512);
      gl_lds16(Bt + (bn + row) * 768 + kb + ss, ldsB + (c * 4 + w) * 512);
    }
    __syncthreads();  // vmcnt drained at barrier -> tile visible
#pragma unroll
    for (int ks = 0; ks < 2; ++ks) {
      s16x8 af[4], bfr[4];
#pragma unroll
      for (int mi = 0; mi < 4; ++mi) {
        const int row = wr * 64 + mi * 16 + ln;
        af[mi] = *(const s16x8*)(lA + row * 128 + (((ks * 4 + kg) ^ (row & 7)) << 4));
      }
#pragma unroll
      for (int ni = 0; ni < 4; ++ni) {
        const int row = wc * 64 + ni * 16 + ln;
        bfr[ni] = *(const s16x8*)(lB + row * 128 + (((ks * 4 + kg) ^ (row & 7)) << 4));
      }
#pragma unroll
      for (int mi = 0; mi < 4; ++mi)
#pragma unroll
        for (int ni = 0; ni < 4; ++ni) acc[mi][ni] = MFMA(af[mi], bfr[ni], acc[mi][ni]);
    }
  }
#pragma unroll
  for (int mi = 0; mi < 4; ++mi)
#pragma unroll
    for (int ni = 0; ni < 4; ++ni) {
      const size_t orow0 = bm + wr * 64 + mi * 16 + kg * 4;
      const size_t ocol = bn + wc * 64 + ni * 16 + ln;
#pragma unroll
      for (int r = 0; r < 4; ++r) obf[(orow0 + r) * 2304 + ocol] = f2b(acc[mi][ni][r]);
    }
}

// ---------- proj GEMM: 128x64 tile (768 blocks -> 3x overlap) + XCD swizzle ----------
__global__ __launch_bounds__(256) void gemm_proj_k(const unsigned short* __restrict__ A,
                                                   const unsigned short* __restrict__ Bt,
                                                   float* __restrict__ out,
                                                   const float* __restrict__ bias) {
  __shared__ unsigned short ldsA[128 * 64];
  __shared__ unsigned short ldsB[64 * 64];
  char* lA = (char*)ldsA;
  char* lB = (char*)ldsB;
  const int t = threadIdx.x, lane = t & 63, w = t >> 6;
  const int ln = lane & 15, kg = lane >> 4;
  // XCD-aware bijective swizzle: nwg=768, 768%8==0
  const int flat = blockIdx.y * 12 + blockIdx.x;
  const int swz = (flat & 7) * 96 + (flat >> 3);
  const size_t bm = (size_t)(swz / 12) * 128, bn = (size_t)(swz % 12) * 64;
  const int wr = w >> 1, wc = w & 1;  // wave -> 64x32 output quadrant
  const int sr = lane >> 3, s = lane & 7;
  f32x4 acc[4][2];
#pragma unroll
  for (int i = 0; i < 4; ++i)
#pragma unroll
    for (int j = 0; j < 2; ++j) acc[i][j] = (f32x4){0.f, 0.f, 0.f, 0.f};

  for (int kb = 0; kb < 768; kb += 64) {
    __syncthreads();
#pragma unroll
    for (int c = 0; c < 4; ++c) {
      const int row = c * 32 + w * 8 + sr;
      const int ss = (s ^ (row & 7)) * 8;
      gl_lds16(A + (bm + row) * 768 + kb + ss, ldsA + (c * 4 + w) * 512);
    }
#pragma unroll
    for (int c = 0; c < 2; ++c) {
      const int row = c * 32 + w * 8 + sr;
      const int ss = (s ^ (row & 7)) * 8;
      gl_lds16(Bt + (bn + row) * 768 + kb + ss, ldsB + (c * 4 + w) * 512);
    }
    __syncthreads();
#pragma unroll
    for (int ks = 0; ks < 2; ++ks) {
      s16x8 af[4], bfr[2];
#pragma unroll
      for (int mi = 0; mi < 4; ++mi) {
        const int row = wr * 64 + mi * 16 + ln;
        af[mi] = *(const s16x8*)(lA + row * 128 + (((ks * 4 + kg) ^ (row & 7)) << 4));
      }
#pragma unroll
      for (int ni = 0; ni < 2; ++ni) {
        const int row = wc * 32 + ni * 16 + ln;
        bfr[ni] = *(const s16x8*)(lB + row * 128 + (((ks * 4 + kg) ^ (row & 7)) << 4));
      }
#pragma unroll
      for (int mi = 0; mi < 4; ++mi)
#pragma unroll
        for (int ni = 0; ni < 2; ++ni) acc[mi][ni] = MFMA(af[mi], bfr[ni], acc[mi][ni]);
    }
  }
#pragma unroll
  for (int mi = 0; mi < 4; ++mi)
#pragma unroll
    for (int ni = 0; ni < 2; ++ni) {
      const size_t orow0 = bm + wr * 64 + mi * 16 + kg * 4;
      const size_t ocol = bn + wc * 32 + ni * 16 + ln;
      const float bv = bias[ocol];
#pragma unroll
      for (int r = 0; r < 4; ++r) out[(orow0 + r) * 768 + ocol] = acc[mi][ni][r] + bv;
    }
}

// ---------- stage 2 helpers ----------
template <int NCT, int CT0>
__device__ inline void s2_gemm2(const char* kfT_b, const char* vt_b, int mts, int ln, int kg,
                                f32x4 (*acc)[3]) {
#pragma unroll
  for (int half = 0; half < 2; ++half) {
    s16x8 a[3], bb[NCT];
#pragma unroll
    for (int j = 0; j < 3; ++j) {
      const int m = (mts + j) * 16 + ln;
      a[j] = *(const s16x8*)(kfT_b + m * 128 + ((half * 64 + kg * 16) ^ ((m & 7) << 4)));
    }
#pragma unroll
    for (int i = 0; i < NCT; ++i) {
      const int c = (CT0 + i) * 16 + ln;
      bb[i] = *(const s16x8*)(vt_b + c * 128 + ((half * 64 + kg * 16) ^ ((c & 7) << 4)));
    }
#pragma unroll
    for (int j = 0; j < 3; ++j)
#pragma unroll
      for (int i = 0; i < NCT; ++i) acc[j][i] = MFMA(a[j], bb[i], acc[j][i]);
  }
}

// ---------- stage 2: phi(k) -> ktv partials (+ksum via ones-column) ----------
// grid (8 = 4 n-groups x 2 m-halves, H, B), 512 threads; stage-early chunk pipeline
__global__ __launch_bounds__(512, 4) void stage2_k(const unsigned short* __restrict__ qkv,
                                                   const unsigned short* __restrict__ wt,
                                                   float* __restrict__ ktv_part,
                                                   float* __restrict__ ksum_part) {
  __shared__ unsigned short kfT[192 * 64];   // [m_local][tok] pitch 128B, swizzled
  __shared__ unsigned short vt[80 * 64];     // [c][tok] pitch 128B, swizzled; row64=1, 65-79=0
  __shared__ unsigned short wt_s[192 * 64];  // [m_local][c] pitch 128B, swizzled
  __shared__ unsigned short k_s[64 * 64];    // [tok][c] pitch 128B, swizzled
  __shared__ float sqh[64];
  char* kfT_b = (char*)kfT;
  char* vt_b = (char*)vt;
  char* wt_b = (char*)wt_s;
  char* k_b = (char*)k_s;
  const int t = threadIdx.x, lane = t & 63, w = t >> 6;
  const int ln = lane & 15, kg = lane >> 4;
  const int gx = blockIdx.x, h = blockIdx.y, b = blockIdx.z;
  const int ng = gx >> 1, mh = gx & 1, m0 = mh * 192;
  const int bh = b * Hn + h;
  const int ntile = w & 3, mgrp = w >> 2;  // GEMM1 assignment
  const int mts = (w & 3) * 3;             // GEMM2: 3 m-tiles per wave
  const int cg = w >> 2;                   // GEMM2: ctiles {0,1,2} or {3,4}
  const int lr = lane >> 3, sl = lane & 7;

  auto stage_k = [&](int ch) {
    const int row = w * 8 + lr;
    gl_lds16(qkv + ((size_t)b * Nn + ng * 512 + ch * 64 + row) * 2304 + 768 + h * 64 +
                 ((sl ^ (row & 7)) * 8),
             k_s + w * 512);
  };
  const int vn = t >> 3, vc0 = (t & 7) * 8;
  auto load_v = [&](int ch) {
    return *(const s16x8*)(qkv + ((size_t)b * Nn + ng * 512 + ch * 64 + vn) * 2304 + 1536 +
                           h * 64 + vc0);
  };
  auto scat_v = [&](s16x8 vv) {
#pragma unroll
    for (int j = 0; j < 8; ++j) {
      const int c = vc0 + j;
      *(unsigned short*)(vt_b + c * 128 + ((2 * vn) ^ ((c & 7) << 4))) = (unsigned short)vv[j];
    }
  };
  auto do_sq = [&]() {
    const int n = t >> 3, slq = t & 7;
    const s16x8 kk = *(const s16x8*)(k_b + n * 128 + ((slq ^ (n & 7)) << 4));
    float sacc = 0.f;
#pragma unroll
    for (int j = 0; j < 8; ++j) {
      const float f = b2f((unsigned short)kk[j]);
      sacc = fmaf(f, f, sacc);
    }
    sacc += __shfl_xor(sacc, 1);
    sacc += __shfl_xor(sacc, 2);
    sacc += __shfl_xor(sacc, 4);
    if ((t & 7) == 0) sqh[n] = 0.5f * SCALE * SCALE * sacc;
  };

  // ---- prologue: wt tile + vt tail init + chunk 0 k/v
#pragma unroll
  for (int rr = 0; rr < 3; ++rr) {
    const int j = w * 3 + rr;  // 1024-B chunk
    const int row = j * 8 + lr;
    gl_lds16(wt + ((size_t)h * 384 + m0 + row) * 64 + ((sl ^ (row & 7)) * 8), wt_s + j * 512);
  }
  for (int i = t; i < 1024; i += 512) {
    const int c = 64 + (i >> 6), nn = i & 63;
    *(unsigned short*)(vt_b + c * 128 + ((2 * nn) ^ ((c & 7) << 4))) =
        (c == 64) ? (unsigned short)0x3F80 : (unsigned short)0;
  }
  stage_k(0);
  s16x8 vreg = load_v(0);
  __syncthreads();  // wt_s, k_s(0), vt-init landed
  scat_v(vreg);
  do_sq();
  __syncthreads();  // vt(0), sqh(0) ready

  f32x4 acc[3][3];
#pragma unroll
  for (int j = 0; j < 3; ++j)
#pragma unroll
    for (int i = 0; i < 3; ++i) acc[j][i] = (f32x4){0.f, 0.f, 0.f, 0.f};

  for (int ch = 0; ch < 8; ++ch) {
    {  // GEMM1: proj k -> exp -> kfT (A from k_s, B from wt_s)
      const int arow = ntile * 16 + ln;
      const s16x8 a0 = *(const s16x8*)(k_b + arow * 128 + ((kg ^ (arow & 7)) << 4));
      const s16x8 a1 = *(const s16x8*)(k_b + arow * 128 + (((kg + 4) ^ (arow & 7)) << 4));
      const int nr = ntile * 16 + kg * 4;
      const float s0 = sqh[nr], s1 = sqh[nr + 1], s2 = sqh[nr + 2], s3 = sqh[nr + 3];
#pragma unroll
      for (int i = 0; i < 6; ++i) {
        const int mloc = (mgrp * 6 + i) * 16 + ln;
        const s16x8 b0 = *(const s16x8*)(wt_b + mloc * 128 + ((kg ^ (mloc & 7)) << 4));
        const s16x8 b1 = *(const s16x8*)(wt_b + mloc * 128 + (((kg + 4) ^ (mloc & 7)) << 4));
        f32x4 p = (f32x4){0.f, 0.f, 0.f, 0.f};
        p = MFMA(a0, b0, p);
        p = MFMA(a1, b1, p);
        const float e0 = __expf(fmaf(SCALE, p[0], -s0)) * ISM;
        const float e1 = __expf(fmaf(SCALE, p[1], -s1)) * ISM;
        const float e2 = __expf(fmaf(SCALE, p[2], -s2)) * ISM;
        const float e3 = __expf(fmaf(SCALE, p[3], -s3)) * ISM;
        uint2 pk;
        pk.x = (unsigned)f2b(e0) | ((unsigned)f2b(e1) << 16);
        pk.y = (unsigned)f2b(e2) | ((unsigned)f2b(e3) << 16);
        const int bytn = 32 * ntile + 8 * kg;
        *(uint2*)(kfT_b + mloc * 128 + (bytn ^ ((mloc & 7) << 4))) = pk;
      }
    }
    __syncthreads();  // kfT visible; all waves done reading k_s(ch)
    if (ch < 7) {     // issue next chunk's k DMA + v reg-load; hide under GEMM2
      stage_k(ch + 1);
      vreg = load_v(ch + 1);
    }
    if (cg == 0)
      s2_gemm2<3, 0>(kfT_b, vt_b, mts, ln, kg, acc);
    else
      s2_gemm2<2, 3>(kfT_b, vt_b, mts, ln, kg, acc);
    __syncthreads();  // GEMM2 done (vt free); vmcnt drained -> k_s(ch+1) landed
    if (ch < 7) {
      scat_v(vreg);
      do_sq();
      __syncthreads();  // vt(ch+1), sqh(ch+1) ready
    }
  }
  // write partials
  float* base = ktv_part + ((size_t)ng * 48 + bh) * (384 * 64);
  const int nct2 = cg ? 2 : 3, ct0c = cg ? 3 : 0;
#pragma unroll
  for (int j = 0; j < 3; ++j)
#pragma unroll
    for (int i = 0; i < 3; ++i) {
      if (i >= nct2) continue;
      const int ct = ct0c + i;
      const int mrow0 = m0 + (mts + j) * 16 + kg * 4;
      if (ct < 4) {
        const int c = ct * 16 + ln;
#pragma unroll
        for (int r = 0; r < 4; ++r) base[(size_t)(mrow0 + r) * 64 + c] = acc[j][i][r];
      } else if (ln == 0) {
#pragma unroll
        for (int r = 0; r < 4; ++r)
          ksum_part[((size_t)ng * 48 + bh) * 384 + mrow0 + r] = acc[j][i][r];
      }
    }
}

// ---------- merged reduction over the 4 n-groups -> ktv_ext [bh][80][384] bf16 ----------
// grid: [0,4608) ktv | [4608,4680) ksum hi/lo
__global__ __launch_bounds__(256) void reduce_all_k(const float* __restrict__ part,
                                                    const float* __restrict__ partk,
                                                    unsigned short* __restrict__ ktve) {
  const int bid = blockIdx.x;
  if (bid < 4608) {
    const int bh = bid / 96, chunk = bid % 96;
    const int idx = chunk * 256 + threadIdx.x;
    const int m = idx >> 6, c = idx & 63;
    const size_t o = (size_t)bh * 24576 + idx;
    const size_t gs = (size_t)48 * 24576;
    const float s = part[o] + part[o + gs] + part[o + 2 * gs] + part[o + 3 * gs];
    ktve[((size_t)bh * 80 + c) * 384 + m] = f2b(s);
  } else {
    const int idx = (bid - 4608) * 256 + threadIdx.x;
    const int bh = idx / 384, m = idx % 384;
    const int gs = 48 * 384;
    const float s = partk[idx] + partk[idx + gs] + partk[idx + 2 * gs] + partk[idx + 3 * gs];
    const unsigned short hi = f2b(s);
    const unsigned short lo = f2b(s - b2f(hi));
    const size_t base = ((size_t)bh * 80 + 64) * 384 + m;
    ktve[base] = hi;
    ktve[base + 384] = lo;
  }
}

// ---------- stage 3: fused phi(q)+attn, all staging coalesced ----------
// grid (16, H, B), 512 threads; 128 tokens/block; 6 m-chunks of 64, dbuf wt/ktve
__global__ __launch_bounds__(512, 4) void stage3_k(const unsigned short* __restrict__ qkv,
                                                   const unsigned short* __restrict__ wt,
                                                   const unsigned short* __restrict__ ktve,
                                                   unsigned short* __restrict__ attn) {
  __shared__ unsigned short q_s[128 * 64];      // [tok][c] swizzled, 16KB
  __shared__ unsigned short qf_s[128 * 64];     // [tok][m_chunk] swizzled, wave-private rows
  __shared__ unsigned short wt_s[2][64 * 64];   // [m][c] swizzled, 8KB each
  __shared__ unsigned short kt_s[2][80 * 64];   // [cext][m_chunk] swizzled, 10KB each
  char* q_b = (char*)q_s;
  char* qf_b = (char*)qf_s;
  const int t = threadIdx.x, lane = t & 63, w = t >> 6;
  const int ln = lane & 15, kg = lane >> 4;
  const int nb = blockIdx.x, h = blockIdx.y, b = blockIdx.z, bh = b * Hn + h;
  const size_t tok0 = (size_t)b * Nn + nb * 128;
  const int lr = lane >> 3, sl = lane & 7;

  // stage q tile (128 rows x 128B), 2 gl_lds16 per wave
#pragma unroll
  for (int rr = 0; rr < 2; ++rr) {
    const int row = w * 16 + rr * 8 + lr;
    gl_lds16(qkv + (tok0 + row) * 2304 + h * 64 + ((sl ^ (row & 7)) * 8),
             q_s + (w * 16 + rr * 8) * 64 + lane * 8);
  }
  // chunk stagers
  auto stage_wt = [&](int mc, int pb) {
    const int row = w * 8 + lr;
    gl_lds16(wt + ((size_t)h * 384 + mc * 64 + row) * 64 + ((sl ^ (row & 7)) * 8),
             wt_s[pb] + w * 512 + lane * 8);
  };
  auto stage_kt = [&](int mc, int pb) {
    const int row = w * 8 + lr;
    gl_lds16(ktve + ((size_t)bh * 80 + row) * 384 + mc * 64 + ((sl ^ (row & 7)) * 8),
             kt_s[pb] + w * 512 + lane * 8);
    if (w < 2) {
      const int row2 = 64 + w * 8 + lr;
      gl_lds16(ktve + ((size_t)bh * 80 + row2) * 384 + mc * 64 + ((sl ^ (row2 & 7)) * 8),
               kt_s[pb] + (64 + w * 8) * 64 + lane * 8);
    }
  };
  stage_wt(0, 0);
  stage_kt(0, 0);
  __syncthreads();  // q + chunk0 ready (barrier drains vmcnt)

  f32x4 acc2[5];
#pragma unroll
  for (int i = 0; i < 5; ++i) acc2[i] = (f32x4){0.f, 0.f, 0.f, 0.f};

  const int arow = w * 16 + ln;          // this wave's A-row (token) for both GEMMs
  const char* qrow = q_b + arow * 128;
  const int asw = (arow & 7) << 4;

  for (int mc = 0; mc < 6; ++mc) {
    const int pb = mc & 1;
    if (mc < 5) {
      stage_wt(mc + 1, pb ^ 1);
      stage_kt(mc + 1, pb ^ 1);
    }
    // GEMM1: proj[tok 16][m 64] for this wave's token tile
    const s16x8 af0 = *(const s16x8*)(qrow + ((kg << 4) ^ asw));
    const s16x8 af1 = *(const s16x8*)(qrow + (((kg + 4) << 4) ^ asw));
    const char* wb = (const char*)wt_s[pb];
    f32x4 p[4];
#pragma unroll
    for (int mt = 0; mt < 4; ++mt) {
      const int mrow = mt * 16 + ln;
      const s16x8 b0 = *(const s16x8*)(wb + mrow * 128 + ((kg ^ (mrow & 7)) << 4));
      const s16x8 b1 = *(const s16x8*)(wb + mrow * 128 + (((kg + 4) ^ (mrow & 7)) << 4));
      f32x4 pp = (f32x4){0.f, 0.f, 0.f, 0.f};
      pp = MFMA(af0, b0, pp);
      p[mt] = MFMA(af1, b1, pp);
    }
    // exp -> qf (wave-private rows; sq_q and ISM cancel in num/D)
#pragma unroll
    for (int mt = 0; mt < 4; ++mt) {
#pragma unroll
      for (int r = 0; r < 4; ++r) {
        const int trow = w * 16 + kg * 4 + r;
        const int m = mt * 16 + ln;
        *(unsigned short*)(qf_b + trow * 128 + ((2 * m) ^ ((trow & 7) << 4))) =
            f2b(__expf(SCALE * p[mt][r]));
      }
    }
    // GEMM2: acc2 += qf(tile) @ kt^T  (same-wave LDS dep only; no barrier)
    const char* qfr = qf_b + arow * 128;
    const s16x8 a0 = *(const s16x8*)(qfr + ((kg << 4) ^ asw));
    const s16x8 a1 = *(const s16x8*)(qfr + (((kg + 4) << 4) ^ asw));
    const char* kb = (const char*)kt_s[pb];
#pragma unroll
    for (int ct = 0; ct < 5; ++ct) {
      const int crow = ct * 16 + ln;
      const s16x8 b0 = *(const s16x8*)(kb + crow * 128 + ((kg ^ (crow & 7)) << 4));
      const s16x8 b1 = *(const s16x8*)(kb + crow * 128 + (((kg + 4) ^ (crow & 7)) << 4));
      acc2[ct] = MFMA(a0, b0, acc2[ct]);
      acc2[ct] = MFMA(a1, b1, acc2[ct]);
    }
    __syncthreads();  // all waves done with buf pb; next stage may overwrite
  }
  // D from c-tile 4 (cols 64=hi, 65=lo) via shuffles; tokens match acc rows
  float dv[4];
#pragma unroll
  for (int r = 0; r < 4; ++r) {
    const float hi = __shfl(acc2[4][r], (lane & 48));
    const float lo = __shfl(acc2[4][r], (lane & 48) | 1);
    dv[r] = 1.0f / (hi + lo + EPS);
  }
#pragma unroll
  for (int ct = 0; ct < 4; ++ct) {
#pragma unroll
    for (int r = 0; r < 4; ++r) {
      const int trow = w * 16 + kg * 4 + r;
      const int c = ct * 16 + ln;
      attn[(tok0 + trow) * 768 + h * 64 + c] = f2b(acc2[ct][r] * dv[r]);
    }
  }
}

}  // namespace

extern "C" void kernel_launch(void* const* d_in, const int* in_sizes, int n_in,
                              void* d_out, int out_size, void* d_ws, size_t ws_size,
                              hipStream_t stream) {
  const float* x = (const float*)d_in[0];
  const float* w = (const float*)d_in[1];
  const float* Wqkv = (const float*)d_in[2];
  const float* Wproj = (const float*)d_in[3];
  const float* bproj = (const float*)d_in[4];

  char* ws = (char*)d_ws;
  unsigned short* xb = (unsigned short*)(ws);
  unsigned short* wqT = (unsigned short*)(ws + 12582912);
  float* ktv_part = (float*)(ws);
  float* ksum_part = (float*)(ws + 18874368);
  char* p = ws + 19169280;
  unsigned short* qkvb = (unsigned short*)p;  p += 37748736;   // (8192,2304) bf16
  unsigned short* wt = (unsigned short*)p;    p += 589824;     // (12,384,64) bf16
  unsigned short* ktve = (unsigned short*)p;  p += 2949120;    // (48,80,384) bf16
  unsigned short* attn = (unsigned short*)p;  p += 12582912;   // (8192,768) bf16
  unsigned short* wpT = (unsigned short*)p;                    // (768,768) bf16

  cvt_all_k<<<4368, 256, 0, stream>>>(x, Wqkv, Wproj, w, xb, wqT, wpT, wt);
  gemm_qkv_k<<<dim3(18, 64), 256, 0, stream>>>(xb, wqT, qkvb);
  stage2_k<<<dim3(8, 12, 4), 512, 0, stream>>>(qkvb, wt, ktv_part, ksum_part);
  reduce_all_k<<<4680, 256, 0, stream>>>(ktv_part, ksum_part, ktve);
  stage3_k<<<dim3(16, 12, 4), 512, 0, stream>>>(qkvb, wt, ktve, attn);
  gemm_proj_k<<<dim3(12, 64), 256, 0, stream>>>(attn, wpT, (float*)d_out, bproj);
}